// Round 11
// baseline (718.344 us; speedup 1.0000x reference)
//
#include <hip/hip_runtime.h>
#include <hip/hip_bf16.h>
#include <cstdint>
#include <cstddef>

typedef unsigned long long u64;
typedef unsigned int u32;
typedef unsigned short ushort_t;

typedef __attribute__((ext_vector_type(8))) short short8;
typedef __attribute__((ext_vector_type(4))) float f32x4;

// ---------------- utilities ----------------
__device__ __forceinline__ u64 shfl_xor_u64(u64 v, int m) {
    u32 lo = (u32)v;
    u32 hi = (u32)(v >> 32);
    lo = __shfl_xor(lo, m, 64);
    hi = __shfl_xor(hi, m, 64);
    return ((u64)hi << 32) | lo;
}

__device__ __forceinline__ ushort_t f2bf(float f) {
    u32 u = __float_as_uint(f);
    u32 r = (u + 0x7fffu + ((u >> 16) & 1u)) >> 16;
    return (ushort_t)r;
}

// sorted-insert key k into ascending top-4
__device__ __forceinline__ void ins4(u64& t0, u64& t1, u64& t2, u64& t3, u64 k) {
    bool c0 = k < t0, c1 = k < t1, c2 = k < t2, c3 = k < t3;
    t3 = c3 ? (c2 ? t2 : k) : t3;
    t2 = c2 ? (c1 ? t1 : k) : t2;
    t1 = c1 ? (c0 ? t0 : k) : t1;
    t0 = c0 ? k : t0;
}

__device__ __forceinline__ void butterfly4(u64& t0, u64& t1, u64& t2, u64& t3) {
    #pragma unroll
    for (int mk = 1; mk < 64; mk <<= 1) {
        u64 o0 = shfl_xor_u64(t0, mk), o1 = shfl_xor_u64(t1, mk);
        u64 o2 = shfl_xor_u64(t2, mk), o3 = shfl_xor_u64(t3, mk);
        ins4(t0, t1, t2, t3, o0);
        ins4(t0, t1, t2, t3, o1);
        ins4(t0, t1, t2, t3, o2);
        ins4(t0, t1, t2, t3, o3);
    }
}

// descending merge of sorted float pairs (a1>=a2), (b1>=b2) -> top-2
__device__ __forceinline__ void merge_desc(float& a1, float& a2, float b1, float b2) {
    float lo = fminf(a1, b1);
    a1 = fmaxf(a1, b1);
    a2 = fmaxf(lo, fmaxf(a2, b2));
}

// ---------------- kernel P: fused prep (x->bf16 | P transpose->bf16 | codes normalize->bf16) ----------------
// grid 4160 x 256: blocks [0,2048) cvt8, [2048,2112) trP, [2112,4160) codes (wave/row).
__global__ __launch_bounds__(256) void k_prep(const float* __restrict__ x,
                                              const float* __restrict__ P,
                                              const float* __restrict__ cb,
                                              ushort_t* __restrict__ xbf,
                                              ushort_t* __restrict__ pbT,
                                              ushort_t* __restrict__ cbf,
                                              u32* __restrict__ count) {
    __shared__ float t[64][65];
    const int b = blockIdx.x;
    const int tid = threadIdx.x;
    if (b == 0 && tid == 0) *count = 0;

    if (b < 2048) {
        // x fp32 -> bf16, 8 elems/thread, 4 grid-stride iters
        const int n8 = 32768 * 512 / 8;
        for (int i = b * 256 + tid; i < n8; i += 2048 * 256) {
            float4 a = ((const float4*)x)[(size_t)i * 2];
            float4 c = ((const float4*)x)[(size_t)i * 2 + 1];
            short8 p;
            p[0] = (short)f2bf(a.x); p[1] = (short)f2bf(a.y);
            p[2] = (short)f2bf(a.z); p[3] = (short)f2bf(a.w);
            p[4] = (short)f2bf(c.x); p[5] = (short)f2bf(c.y);
            p[6] = (short)f2bf(c.z); p[7] = (short)f2bf(c.w);
            ((short8*)xbf)[i] = p;
        }
    } else if (b < 2112) {
        // P [k][n] -> PT [n][k] bf16
        const int bb = b - 2048;
        const int kb = (bb & 7) * 64;
        const int nb = (bb >> 3) * 64;
        const int tx = tid & 63;
        const int ty = tid >> 6;
        #pragma unroll
        for (int r = ty; r < 64; r += 4) t[r][tx] = P[(size_t)(kb + r) * 512 + nb + tx];
        __syncthreads();
        #pragma unroll
        for (int r = ty; r < 64; r += 4)
            pbT[(size_t)(nb + r) * 512 + kb + tx] = f2bf(t[tx][r]);
    } else {
        // codebook row normalize (fp64), one wave per row
        const int row = (b - 2112) * 4 + (tid >> 6);
        const int lane = tid & 63;
        const float* src = cb + (size_t)row * 512 + lane * 8;
        float4 v0 = *(const float4*)src;
        float4 v1 = *(const float4*)(src + 4);
        double s = (double)v0.x * v0.x + (double)v0.y * v0.y + (double)v0.z * v0.z + (double)v0.w * v0.w
                 + (double)v1.x * v1.x + (double)v1.y * v1.y + (double)v1.z * v1.z + (double)v1.w * v1.w;
        #pragma unroll
        for (int mk = 1; mk < 64; mk <<= 1) s += __shfl_xor(s, mk, 64);
        double inv = 1.0 / fmax(sqrt(s), 1e-12);
        short8 o;
        o[0] = (short)f2bf((float)((double)v0.x * inv));
        o[1] = (short)f2bf((float)((double)v0.y * inv));
        o[2] = (short)f2bf((float)((double)v0.z * inv));
        o[3] = (short)f2bf((float)((double)v0.w * inv));
        o[4] = (short)f2bf((float)((double)v1.x * inv));
        o[5] = (short)f2bf((float)((double)v1.y * inv));
        o[6] = (short)f2bf((float)((double)v1.z * inv));
        o[7] = (short)f2bf((float)((double)v1.w * inv));
        *(short8*)(cbf + (size_t)row * 512 + lane * 8) = o;
    }
}

// ---------------- kernel 2: projection GEMM ybf = xbf @ PT^T via MFMA (proven) ----------------
__global__ __launch_bounds__(256) void k_proj(const ushort_t* __restrict__ X,
                                              const ushort_t* __restrict__ PT,
                                              ushort_t* __restrict__ Ybf) {
    __shared__ ushort_t Ab[128 * 64];
    __shared__ ushort_t Bb[128 * 64];
    const int tid = threadIdx.x;
    const int lane = tid & 63;
    const int wid = tid >> 6;
    const int wm = wid & 1, wn = wid >> 1;
    const int rowBase = blockIdx.x * 128;
    const int colBase = blockIdx.y * 128;

    const ushort_t* asrc[4];
    const ushort_t* bsrc[4];
    int ldsoff[4];
    #pragma unroll
    for (int i = 0; i < 4; i++) {
        const int L = i * 256 + tid;
        const int r = L >> 3;
        const int s = (L & 7) ^ (r & 7);
        asrc[i] = X + (size_t)(rowBase + r) * 512 + s * 8;
        bsrc[i] = PT + (size_t)(colBase + r) * 512 + s * 8;
        ldsoff[i] = (i * 256 + (tid & ~63)) * 16;
    }

    f32x4 acc[4][4];
    #pragma unroll
    for (int i = 0; i < 4; i++)
        #pragma unroll
        for (int j = 0; j < 4; j++) {
            f32x4 z = {0.f, 0.f, 0.f, 0.f};
            acc[i][j] = z;
        }

    int aoff[4][2], boff[4][2];
    #pragma unroll
    for (int ti = 0; ti < 4; ti++)
        #pragma unroll
        for (int ks = 0; ks < 2; ks++) {
            const int sa = ks * 4 + (lane >> 4);
            const int ra = wm * 64 + ti * 16 + (lane & 15);
            aoff[ti][ks] = (ra * 8 + (sa ^ (ra & 7))) * 8;
            const int rb = wn * 64 + ti * 16 + (lane & 15);
            boff[ti][ks] = (rb * 8 + (sa ^ (rb & 7))) * 8;
        }

    for (int kt = 0; kt < 512; kt += 64) {
        #pragma unroll
        for (int i = 0; i < 4; i++) {
            __builtin_amdgcn_global_load_lds(
                (const __attribute__((address_space(1))) uint32_t*)(asrc[i] + kt),
                (__attribute__((address_space(3))) uint32_t*)((char*)Ab + ldsoff[i]), 16, 0, 0);
            __builtin_amdgcn_global_load_lds(
                (const __attribute__((address_space(1))) uint32_t*)(bsrc[i] + kt),
                (__attribute__((address_space(3))) uint32_t*)((char*)Bb + ldsoff[i]), 16, 0, 0);
        }
        __syncthreads();
        short8 af[4][2], bfr[4][2];
        #pragma unroll
        for (int ti = 0; ti < 4; ti++)
            #pragma unroll
            for (int ks = 0; ks < 2; ks++) {
                af[ti][ks]  = *(const short8*)(Ab + aoff[ti][ks]);
                bfr[ti][ks] = *(const short8*)(Bb + boff[ti][ks]);
            }
        #pragma unroll
        for (int ks = 0; ks < 2; ks++)
            #pragma unroll
            for (int ti = 0; ti < 4; ti++)
                #pragma unroll
                for (int tj = 0; tj < 4; tj++)
                    acc[ti][tj] = __builtin_amdgcn_mfma_f32_16x16x32_bf16(
                        af[ti][ks], bfr[tj][ks], acc[ti][tj], 0, 0, 0);
        __syncthreads();
    }

    #pragma unroll
    for (int ti = 0; ti < 4; ti++)
        #pragma unroll
        for (int tj = 0; tj < 4; tj++) {
            const int col = colBase + wn * 64 + tj * 16 + (lane & 15);
            #pragma unroll
            for (int reg = 0; reg < 4; reg++) {
                const int row = rowBase + wm * 64 + ti * 16 + (lane >> 4) * 4 + reg;
                Ybf[(size_t)row * 512 + col] = f2bf(acc[ti][tj][reg]);
            }
        }
}

// ---------------- kernel 3: bf16 MFMA GEMM 256x128, 4-phase K-half pipeline (1 block/CU, 8 waves) ----------------
// grid (128, 64), 512 thr = 8 waves (4 wm x 2 wn), wave tile 64x64.
// LDS regions [buf][khalf]: A 2x2x16KB, B 2x2x8KB (+8KB tmp) = 104 KB -> 1 block/CU.
// Schedule: tile u's K0 staged in iter u-2 ph2-3 (into region freed at that iter's mid-barrier);
// K1 staged in iter u-1 ph0-1. Counted vmcnt(6) at both barriers (tail: 3, 0) -- no mid-loop drain.
// FIFO proof: at each boundary exactly the 2 younger K-half groups (6 loads) remain in flight.
// Slot swizzle (4 slots/row): phys p = (s + (r>>1)) & 3 (round-10-proven, conflict-free);
// staging source pre-inverse-swizzled, LDS dest linear (rule #21).
__global__ __launch_bounds__(512) void k_gemm(const ushort_t* __restrict__ Y,
                                              const ushort_t* __restrict__ C,
                                              u32* __restrict__ part2) {
    __shared__ ushort_t Ab[2][2][256 * 32];   // [buf][khalf][256 rows x 4 slots x 8] = 16 KB each
    __shared__ ushort_t Bb[2][2][128 * 32];   // 8 KB each
    __shared__ u32 tmp[256][2][2][2];         // 8 KB
    const int tid = threadIdx.x;
    const int lane = tid & 63;
    const int wid = tid >> 6;
    const int wm = wid >> 1, wn = wid & 1;    // wm 0..3 (rows), wn 0..1 (cols)
    const int rowBase = blockIdx.x * 256;
    const int colBase = blockIdx.y * 128;

    // staging maps (K-half granularity): A 2 loads (rows 0-127, 128-255), B 1 load
    const int La0 = tid, La1 = 512 + tid, Lb = tid;
    const int ra0 = La0 >> 2, ra1 = La1 >> 2, rb = Lb >> 2;
    const int sa0 = ((La0 & 3) - (ra0 >> 1)) & 3;
    const int sa1 = ((La1 & 3) - (ra1 >> 1)) & 3;
    const int sb  = ((Lb & 3) - (rb >> 1)) & 3;
    const ushort_t* aSrc0 = Y + (size_t)(rowBase + ra0) * 512 + sa0 * 8;
    const ushort_t* aSrc1 = Y + (size_t)(rowBase + ra1) * 512 + sa1 * 8;
    const ushort_t* bSrc  = C + (size_t)(colBase + rb) * 512 + sb * 8;
    const int aLds0 = (La0 & ~63) * 16;       // byte offset within 16 KB region (wave-uniform base)
    const int aLds1 = (La1 & ~63) * 16;
    const int bLds  = (Lb & ~63) * 16;

    f32x4 acc[4][4];
    #pragma unroll
    for (int i = 0; i < 4; i++)
        #pragma unroll
        for (int j = 0; j < 4; j++) {
            f32x4 z = {16.f, 16.f, 16.f, 16.f};
            acc[i][j] = z;
        }

    // fragment read byte-offsets within a [rows][4 slots] region; q = lane>>4 logical slot
    int aoffB[4], boffB[4];
    #pragma unroll
    for (int ti = 0; ti < 4; ti++) {
        const int ra = wm * 64 + ti * 16 + (lane & 15);
        aoffB[ti] = (ra * 32 + (((lane >> 4) + (ra >> 1)) & 3) * 8) * 2;
        const int rc = wn * 64 + ti * 16 + (lane & 15);
        boffB[ti] = (rc * 32 + (((lane >> 4) + (rc >> 1)) & 3) * 8) * 2;
    }

    u32 ecol[4];
    #pragma unroll
    for (int tj = 0; tj < 4; tj++) ecol[tj] = 127u - (u32)(wn * 64 + tj * 16 + (lane & 15));

#define GLL16(srcp, dstp)                                                        \
    __builtin_amdgcn_global_load_lds(                                            \
        (const __attribute__((address_space(1))) uint32_t*)(srcp),               \
        (__attribute__((address_space(3))) uint32_t*)(dstp), 16, 0, 0)
#define STAGE_A(buf, kh, koff) do {                                              \
    GLL16(aSrc0 + (koff), (char*)&Ab[buf][kh][0] + aLds0);                       \
    GLL16(aSrc1 + (koff), (char*)&Ab[buf][kh][0] + aLds1);                       \
} while (0)
#define STAGE_B(buf, kh, koff) GLL16(bSrc + (koff), (char*)&Bb[buf][kh][0] + bLds)
#define RDA(buf, kh, ti_) (*(const short8*)((const char*)&Ab[buf][kh][0] + aoffB[ti_]))
#define RDB(buf, kh, tj_) (*(const short8*)((const char*)&Bb[buf][kh][0] + boffB[tj_]))

    // prologue: tile0-K0, tile0-K1, tile1-K0  (9 loads)
    STAGE_A(0, 0, 0);  STAGE_B(0, 0, 0);
    STAGE_A(0, 1, 32); STAGE_B(0, 1, 32);
    STAGE_A(1, 0, 64); STAGE_B(1, 0, 64);

    #pragma unroll
    for (int t = 0; t < 8; ++t) {
        const int b = t & 1;
        // ---- boundary 0: need tile t K0 landed; {t+1 K0, t K1} may fly (6) ----
        if (t < 7) { asm volatile("s_waitcnt vmcnt(6)" ::: "memory"); }
        else       { asm volatile("s_waitcnt vmcnt(3)" ::: "memory"); }
        __builtin_amdgcn_sched_barrier(0);
        __builtin_amdgcn_s_barrier();
        __builtin_amdgcn_sched_barrier(0);
        // ---- ph0: mh=0, kh=0 ----
        short8 af0 = RDA(b, 0, 0), af1 = RDA(b, 0, 1);
        short8 bf0 = RDB(b, 0, 0), bf1 = RDB(b, 0, 1), bf2 = RDB(b, 0, 2), bf3 = RDB(b, 0, 3);
        if (t + 1 < 8) STAGE_A(!b, 1, (t + 1) * 64 + 32);   // tile t+1 K1 (A)
        __builtin_amdgcn_s_setprio(1);
        acc[0][0] = __builtin_amdgcn_mfma_f32_16x16x32_bf16(af0, bf0, acc[0][0], 0, 0, 0);
        acc[0][1] = __builtin_amdgcn_mfma_f32_16x16x32_bf16(af0, bf1, acc[0][1], 0, 0, 0);
        acc[0][2] = __builtin_amdgcn_mfma_f32_16x16x32_bf16(af0, bf2, acc[0][2], 0, 0, 0);
        acc[0][3] = __builtin_amdgcn_mfma_f32_16x16x32_bf16(af0, bf3, acc[0][3], 0, 0, 0);
        acc[1][0] = __builtin_amdgcn_mfma_f32_16x16x32_bf16(af1, bf0, acc[1][0], 0, 0, 0);
        acc[1][1] = __builtin_amdgcn_mfma_f32_16x16x32_bf16(af1, bf1, acc[1][1], 0, 0, 0);
        acc[1][2] = __builtin_amdgcn_mfma_f32_16x16x32_bf16(af1, bf2, acc[1][2], 0, 0, 0);
        acc[1][3] = __builtin_amdgcn_mfma_f32_16x16x32_bf16(af1, bf3, acc[1][3], 0, 0, 0);
        __builtin_amdgcn_s_setprio(0);
        // ---- ph1: mh=1, kh=0 ----
        short8 af2 = RDA(b, 0, 2), af3 = RDA(b, 0, 3);
        if (t + 1 < 8) STAGE_B(!b, 1, (t + 1) * 64 + 32);   // tile t+1 K1 (B)
        __builtin_amdgcn_s_setprio(1);
        acc[2][0] = __builtin_amdgcn_mfma_f32_16x16x32_bf16(af2, bf0, acc[2][0], 0, 0, 0);
        acc[2][1] = __builtin_amdgcn_mfma_f32_16x16x32_bf16(af2, bf1, acc[2][1], 0, 0, 0);
        acc[2][2] = __builtin_amdgcn_mfma_f32_16x16x32_bf16(af2, bf2, acc[2][2], 0, 0, 0);
        acc[2][3] = __builtin_amdgcn_mfma_f32_16x16x32_bf16(af2, bf3, acc[2][3], 0, 0, 0);
        acc[3][0] = __builtin_amdgcn_mfma_f32_16x16x32_bf16(af3, bf0, acc[3][0], 0, 0, 0);
        acc[3][1] = __builtin_amdgcn_mfma_f32_16x16x32_bf16(af3, bf1, acc[3][1], 0, 0, 0);
        acc[3][2] = __builtin_amdgcn_mfma_f32_16x16x32_bf16(af3, bf2, acc[3][2], 0, 0, 0);
        acc[3][3] = __builtin_amdgcn_mfma_f32_16x16x32_bf16(af3, bf3, acc[3][3], 0, 0, 0);
        __builtin_amdgcn_s_setprio(0);
        // ---- boundary 1: need tile t K1 landed; {t+1 K1, t+1 K0} may fly (6) ----
        if (t < 7) { asm volatile("s_waitcnt vmcnt(6)" ::: "memory"); }
        else       { asm volatile("s_waitcnt vmcnt(0)" ::: "memory"); }
        __builtin_amdgcn_sched_barrier(0);
        __builtin_amdgcn_s_barrier();
        __builtin_amdgcn_sched_barrier(0);
        // ---- ph2: mh=0, kh=1 ----
        af0 = RDA(b, 1, 0); af1 = RDA(b, 1, 1);
        bf0 = RDB(b, 1, 0); bf1 = RDB(b, 1, 1); bf2 = RDB(b, 1, 2); bf3 = RDB(b, 1, 3);
        if (t + 2 < 8) STAGE_A(b, 0, (t + 2) * 64);         // tile t+2 K0 (A) -> region freed at boundary 1
        __builtin_amdgcn_s_setprio(1);
        acc[0][0] = __builtin_amdgcn_mfma_f32_16x16x32_bf16(af0, bf0, acc[0][0], 0, 0, 0);
        acc[0][1] = __builtin_amdgcn_mfma_f32_16x16x32_bf16(af0, bf1, acc[0][1], 0, 0, 0);
        acc[0][2] = __builtin_amdgcn_mfma_f32_16x16x32_bf16(af0, bf2, acc[0][2], 0, 0, 0);
        acc[0][3] = __builtin_amdgcn_mfma_f32_16x16x32_bf16(af0, bf3, acc[0][3], 0, 0, 0);
        acc[1][0] = __builtin_amdgcn_mfma_f32_16x16x32_bf16(af1, bf0, acc[1][0], 0, 0, 0);
        acc[1][1] = __builtin_amdgcn_mfma_f32_16x16x32_bf16(af1, bf1, acc[1][1], 0, 0, 0);
        acc[1][2] = __builtin_amdgcn_mfma_f32_16x16x32_bf16(af1, bf2, acc[1][2], 0, 0, 0);
        acc[1][3] = __builtin_amdgcn_mfma_f32_16x16x32_bf16(af1, bf3, acc[1][3], 0, 0, 0);
        __builtin_amdgcn_s_setprio(0);
        // ---- ph3: mh=1, kh=1 ----
        af2 = RDA(b, 1, 2); af3 = RDA(b, 1, 3);
        if (t + 2 < 8) STAGE_B(b, 0, (t + 2) * 64);         // tile t+2 K0 (B)
        __builtin_amdgcn_s_setprio(1);
        acc[2][0] = __builtin_amdgcn_mfma_f32_16x16x32_bf16(af2, bf0, acc[2][0], 0, 0, 0);
        acc[2][1] = __builtin_amdgcn_mfma_f32_16x16x32_bf16(af2, bf1, acc[2][1], 0, 0, 0);
        acc[2][2] = __builtin_amdgcn_mfma_f32_16x16x32_bf16(af2, bf2, acc[2][2], 0, 0, 0);
        acc[2][3] = __builtin_amdgcn_mfma_f32_16x16x32_bf16(af2, bf3, acc[2][3], 0, 0, 0);
        acc[3][0] = __builtin_amdgcn_mfma_f32_16x16x32_bf16(af3, bf0, acc[3][0], 0, 0, 0);
        acc[3][1] = __builtin_amdgcn_mfma_f32_16x16x32_bf16(af3, bf1, acc[3][1], 0, 0, 0);
        acc[3][2] = __builtin_amdgcn_mfma_f32_16x16x32_bf16(af3, bf2, acc[3][2], 0, 0, 0);
        acc[3][3] = __builtin_amdgcn_mfma_f32_16x16x32_bf16(af3, bf3, acc[3][3], 0, 0, 0);
        __builtin_amdgcn_s_setprio(0);
    }
#undef GLL16
#undef STAGE_A
#undef STAGE_B
#undef RDA
#undef RDB

    // epilogue: embed col, per-thread top-2 of 4 cols, 3-step butterfly (8-lane groups)
    #pragma unroll
    for (int ti = 0; ti < 4; ti++)
        #pragma unroll
        for (int reg = 0; reg < 4; reg++) {
            float v0 = __uint_as_float((__float_as_uint(acc[ti][0][reg]) & 0xFFFFFF80u) | ecol[0]);
            float v1 = __uint_as_float((__float_as_uint(acc[ti][1][reg]) & 0xFFFFFF80u) | ecol[1]);
            float v2 = __uint_as_float((__float_as_uint(acc[ti][2][reg]) & 0xFFFFFF80u) | ecol[2]);
            float v3 = __uint_as_float((__float_as_uint(acc[ti][3][reg]) & 0xFFFFFF80u) | ecol[3]);
            float m1 = fmaxf(v0, v1);
            float m2 = fminf(v0, v1);
            float med = __builtin_amdgcn_fmed3f(m1, v2, v3);
            m1 = fmaxf(m1, fmaxf(v2, v3));
            m2 = fmaxf(m2, med);
            #pragma unroll
            for (int mk = 1; mk < 8; mk <<= 1) {
                float o1 = __shfl_xor(m1, mk, 64);
                float o2 = __shfl_xor(m2, mk, 64);
                merge_desc(m1, m2, o1, o2);
            }
            if ((lane & 7) == 0) {
                const int mrow = wm * 64 + ti * 16 + (lane >> 4) * 4 + reg;
                const int grp = (lane >> 3) & 1;
                tmp[mrow][wn][grp][0] = __float_as_uint(m1);
                tmp[mrow][wn][grp][1] = __float_as_uint(m2);
            }
        }
    __syncthreads();
    if (tid < 256) {
        float a1 = __uint_as_float(tmp[tid][0][0][0]), a2 = __uint_as_float(tmp[tid][0][0][1]);
        merge_desc(a1, a2, __uint_as_float(tmp[tid][0][1][0]), __uint_as_float(tmp[tid][0][1][1]));
        merge_desc(a1, a2, __uint_as_float(tmp[tid][1][0][0]), __uint_as_float(tmp[tid][1][0][1]));
        merge_desc(a1, a2, __uint_as_float(tmp[tid][1][1][0]), __uint_as_float(tmp[tid][1][1][1]));
        u32* dst = part2 + ((size_t)(rowBase + tid) * 64 + blockIdx.y) * 2;
        dst[0] = __float_as_uint(a1);
        dst[1] = __float_as_uint(a2);
    }
}

// ---------------- kernel 4: float-domain winner + margin flag (round-6-proven threshold) ----------------
// grid 8192 x 256 (wave per row).
__global__ __launch_bounds__(256) void k_pick(const u32* __restrict__ part2,
                                              const int* __restrict__ mask,
                                              int* __restrict__ out,
                                              u32* __restrict__ wl,
                                              u32* __restrict__ count) {
    const int row = blockIdx.x * 4 + (threadIdx.x >> 6);
    const int lane = threadIdx.x & 63;
    const u32* base = part2 + (size_t)row * 128;
    const u32 b0 = base[lane];
    const u32 b1 = base[64 + lane];
    // all keys are positive floats -> u32 order == float order
    float a1 = __uint_as_float(b0 > b1 ? b0 : b1);
    float a2 = __uint_as_float(b0 > b1 ? b1 : b0);
    #pragma unroll
    for (int mk = 1; mk < 64; mk <<= 1) {
        float o1 = __shfl_xor(a1, mk, 64);
        float o2 = __shfl_xor(a2, mk, 64);
        merge_desc(a1, a2, o1, o2);
    }
    // decode winner's global col: min col among keys bit-equal to the max
    const u32 w1 = __float_as_uint(a1);
    u32 c0 = (b0 == w1) ? ((u32)(lane >> 1) * 128u + (127u - (b0 & 0x7Fu))) : 0xFFFFu;
    u32 c1 = (b1 == w1) ? ((u32)((64 + lane) >> 1) * 128u + (127u - (b1 & 0x7Fu))) : 0xFFFFu;
    u32 cmin = c0 < c1 ? c0 : c1;
    #pragma unroll
    for (int mk = 1; mk < 64; mk <<= 1) {
        u32 oc = __shfl_xor(cmin, mk, 64);
        cmin = cmin < oc ? cmin : oc;
    }
    if (lane == 0) {
        out[row] = mask[row] ? (int)cmin : 0;
        // margin noise sigma ~= 2.3e-3 (bf16 operands, ||y||~22.6); round-6-proven
        // threshold = 0.006*|score| + 0.002 ~= 10 sigma at typical score 3.7.
        const float s1 = a1 - 16.0f;
        if (a1 - a2 < 0.006f * fabsf(s1) + 0.002f) {
            u32 pos = atomicAdd(count, 1u);
            wl[pos] = (u32)row;
        }
    }
}

// ---------------- kernel 5: exact fp64 fix; extracts its own top-8 from part2 ----------------
// grid 256 x 256, grid-stride over worklist; 16 rows/block.
__global__ __launch_bounds__(256) void k_fix16(const float* __restrict__ x,
                                               const float* __restrict__ P,
                                               const float* __restrict__ cb,
                                               const u32* __restrict__ part2,
                                               const u32* __restrict__ wl,
                                               const u32* __restrict__ count,
                                               const int* __restrict__ mask,
                                               int* __restrict__ out) {
    __shared__ float xs[16][512];
    __shared__ u32 cands_s[16][8];
    __shared__ double nrmw[4][16];
    __shared__ double invn[16];
    __shared__ double wredD[4][8];
    __shared__ double wredC[4][8];
    __shared__ int bestIdx[16];
    const int tid = threadIdx.x;
    const int lane = tid & 63;
    const int wv = tid >> 6;
    const u32 n = *count;

    for (u32 basei = (u32)blockIdx.x * 16u; basei < n; basei += (u32)gridDim.x * 16u) {
        const int nr = (int)((n - basei < 16u) ? (n - basei) : 16u);
        __syncthreads();

        // stage x rows
        {
            const int r = tid >> 4;
            const int rc = r < nr ? r : nr - 1;
            const u32 ridx = wl[basei + rc];
            const float4* src = (const float4*)(x + (size_t)ridx * 512);
            float4* dst = (float4*)&xs[r][0];
            const int c = tid & 15;
            #pragma unroll
            for (int j = 0; j < 8; j++) dst[c + j * 16] = src[c + j * 16];
        }
        // extract top-8 candidates per row from part2 (u64 keys, exact order + col tiebreak)
        for (int rr = wv; rr < 16; rr += 4) {
            const int rc = rr < nr ? rr : nr - 1;
            const u32 rowi = wl[basei + rc];
            const u32* base = part2 + (size_t)rowi * 128;
            const u32 b0 = base[lane];
            const u32 b1 = base[64 + lane];
            const u32 sc0 = b0 & 0xFFFFFF80u;
            const u32 sc1 = b1 & 0xFFFFFF80u;
            const u32 col0 = (u32)(lane >> 1) * 128u + (127u - (b0 & 0x7Fu));
            const u32 col1 = (u32)((64 + lane) >> 1) * 128u + (127u - (b1 & 0x7Fu));
            const u64 k0 = ((u64)(~sc0) << 13) | col0;
            const u64 k1 = ((u64)(~sc1) << 13) | col1;
            u64 t0 = k0 < k1 ? k0 : k1;
            u64 t1 = k0 < k1 ? k1 : k0;
            u64 t2 = ~0ull, t3 = ~0ull;
            butterfly4(t0, t1, t2, t3);
            const u64 g0 = t0, g1 = t1, g2 = t2, g3 = t3;
            u64 e0 = (k0 == g0 || k0 == g1 || k0 == g2 || k0 == g3) ? ~0ull : k0;
            u64 e1 = (k1 == g0 || k1 == g1 || k1 == g2 || k1 == g3) ? ~0ull : k1;
            u64 u0 = e0 < e1 ? e0 : e1;
            u64 u1 = e0 < e1 ? e1 : e0;
            u64 u2 = ~0ull, u3 = ~0ull;
            butterfly4(u0, u1, u2, u3);
            if (lane == 0) {
                cands_s[rr][0] = (u32)(g0 & 0x1FFFu); cands_s[rr][1] = (u32)(g1 & 0x1FFFu);
                cands_s[rr][2] = (u32)(g2 & 0x1FFFu); cands_s[rr][3] = (u32)(g3 & 0x1FFFu);
                cands_s[rr][4] = (u32)(u0 & 0x1FFFu); cands_s[rr][5] = (u32)(u1 & 0x1FFFu);
                cands_s[rr][6] = (u32)(u2 & 0x1FFFu); cands_s[rr][7] = (u32)(u3 & 0x1FFFu);
            }
        }
        __syncthreads();

        // fp64 projection: thread owns columns d0, d0+1 for all 16 rows
        const int d0 = tid * 2;
        double acc[16][2];
        #pragma unroll
        for (int r = 0; r < 16; r++) { acc[r][0] = 0.0; acc[r][1] = 0.0; }
        const float* pp = P + d0;
        for (int k = 0; k < 512; k += 2) {
            float2 pa = *(const float2*)(pp + (size_t)k * 512);
            float2 pb = *(const float2*)(pp + (size_t)(k + 1) * 512);
            const double pa0 = (double)pa.x, pa1 = (double)pa.y;
            const double pb0 = (double)pb.x, pb1 = (double)pb.y;
            #pragma unroll
            for (int r = 0; r < 16; r++) {
                float2 xv = *(const float2*)&xs[r][k];
                const double x0 = (double)xv.x, x1 = (double)xv.y;
                acc[r][0] = fma(x0, pa0, acc[r][0]);
                acc[r][1] = fma(x0, pa1, acc[r][1]);
                acc[r][0] = fma(x1, pb0, acc[r][0]);
                acc[r][1] = fma(x1, pb1, acc[r][1]);
            }
        }

        // fp64 row norms
        #pragma unroll
        for (int r = 0; r < 16; r++) {
            double s = fma(acc[r][0], acc[r][0], acc[r][1] * acc[r][1]);
            #pragma unroll
            for (int mk = 1; mk < 64; mk <<= 1) s += __shfl_xor(s, mk, 64);
            if (lane == 0) nrmw[wv][r] = s;
        }
        __syncthreads();
        if (tid < 16) {
            double t = nrmw[0][tid] + nrmw[1][tid] + nrmw[2][tid] + nrmw[3][tid];
            invn[tid] = 1.0 / fmax(sqrt(t), 1e-12);
        }
        __syncthreads();

        // rescore 8 candidates per row in fp64 from raw codebooks
        for (int r = 0; r < nr; r++) {
            const double xinv = invn[r];
            const double xn0 = acc[r][0] * xinv;
            const double xn1 = acc[r][1] * xinv;
            int vidx[8];
            double pd[8], pc[8];
            #pragma unroll
            for (int c = 0; c < 8; c++) {
                vidx[c] = (int)cands_s[r][c];
                float2 cv = *(const float2*)(cb + (size_t)vidx[c] * 512 + d0);
                const double c0 = (double)cv.x, c1 = (double)cv.y;
                pd[c] = fma(c0, xn0, c1 * xn1);
                pc[c] = fma(c0, c0, c1 * c1);
            }
            #pragma unroll
            for (int mk = 1; mk < 64; mk <<= 1) {
                #pragma unroll
                for (int c = 0; c < 8; c++) {
                    pd[c] += __shfl_xor(pd[c], mk, 64);
                    pc[c] += __shfl_xor(pc[c], mk, 64);
                }
            }
            if (lane == 0) {
                #pragma unroll
                for (int c = 0; c < 8; c++) { wredD[wv][c] = pd[c]; wredC[wv][c] = pc[c]; }
            }
            __syncthreads();
            if (tid == 0) {
                double bs = -1.0e300;
                int bi = 0x7fffffff;
                #pragma unroll
                for (int c = 0; c < 8; c++) {
                    const double D = wredD[0][c] + wredD[1][c] + wredD[2][c] + wredD[3][c];
                    const double Cw = wredC[0][c] + wredC[1][c] + wredC[2][c] + wredC[3][c];
                    const double s = D / fmax(sqrt(Cw), 1e-12);
                    const int v = vidx[c];
                    if (s > bs || (s == bs && v < bi)) { bs = s; bi = v; }
                }
                bestIdx[r] = bi;
            }
            __syncthreads();
        }

        if (tid < nr) {
            const u32 row = wl[basei + tid];
            out[row] = mask[row] ? bestIdx[tid] : 0;
        }
    }
}

// ---------------- launcher ----------------
extern "C" void kernel_launch(void* const* d_in, const int* in_sizes, int n_in,
                              void* d_out, int out_size, void* d_ws, size_t ws_size,
                              hipStream_t stream) {
    const float* x = (const float*)d_in[0];               // [32768,512] fp32
    const int* mask = (const int*)d_in[1];                // [32768] bool->int32
    const float* projection = (const float*)d_in[2];      // [512,512] fp32
    const float* codebooks = (const float*)d_in[3];       // [8192,512] fp32
    int* out = (int*)d_out;                               // [32768] int32

    // workspace (~75 MB): xbf dead after k_proj -> part2 aliases it.
    char* ws = (char*)d_ws;
    ushort_t* xbf = (ushort_t*)ws;                         // 32 MB [0,32)
    u32* part2    = (u32*)ws;                              // 16 MB (aliases xbf)
    ushort_t* ybf = (ushort_t*)(ws + (32u << 20));         // 32 MB [32,64)
    ushort_t* cbf = (ushort_t*)(ws + (64u << 20));         // 8 MB  [64,72)
    ushort_t* pbT = (ushort_t*)(ws + (72u << 20));         // 512 KB
    u32* wl       = (u32*)(ws + (73u << 20));              // 128 KB
    u32* count    = (u32*)(ws + (74u << 20));              // 4 B

    k_prep<<<4160, 256, 0, stream>>>(x, projection, codebooks, xbf, pbT, cbf, count);
    k_proj<<<dim3(256, 4), 256, 0, stream>>>(xbf, pbT, ybf);
    k_gemm<<<dim3(128, 64), 512, 0, stream>>>(ybf, cbf, part2);
    k_pick<<<8192, 256, 0, stream>>>(part2, mask, out, wl, count);
    k_fix16<<<256, 256, 0, stream>>>(x, projection, codebooks, part2, wl, count,
                                     mask, out);
}

// Round 12
// 669.284 us; speedup vs baseline: 1.0733x; 1.0733x over previous
//
#include <hip/hip_runtime.h>
#include <hip/hip_bf16.h>
#include <cstdint>
#include <cstddef>

typedef unsigned long long u64;
typedef unsigned int u32;
typedef unsigned short ushort_t;

typedef __attribute__((ext_vector_type(8))) short short8;
typedef __attribute__((ext_vector_type(4))) float f32x4;

// ---------------- utilities ----------------
__device__ __forceinline__ u64 shfl_xor_u64(u64 v, int m) {
    u32 lo = (u32)v;
    u32 hi = (u32)(v >> 32);
    lo = __shfl_xor(lo, m, 64);
    hi = __shfl_xor(hi, m, 64);
    return ((u64)hi << 32) | lo;
}

__device__ __forceinline__ ushort_t f2bf(float f) {
    u32 u = __float_as_uint(f);
    u32 r = (u + 0x7fffu + ((u >> 16) & 1u)) >> 16;
    return (ushort_t)r;
}

// sorted-insert key k into ascending top-4
__device__ __forceinline__ void ins4(u64& t0, u64& t1, u64& t2, u64& t3, u64 k) {
    bool c0 = k < t0, c1 = k < t1, c2 = k < t2, c3 = k < t3;
    t3 = c3 ? (c2 ? t2 : k) : t3;
    t2 = c2 ? (c1 ? t1 : k) : t2;
    t1 = c1 ? (c0 ? t0 : k) : t1;
    t0 = c0 ? k : t0;
}

__device__ __forceinline__ void butterfly4(u64& t0, u64& t1, u64& t2, u64& t3) {
    #pragma unroll
    for (int mk = 1; mk < 64; mk <<= 1) {
        u64 o0 = shfl_xor_u64(t0, mk), o1 = shfl_xor_u64(t1, mk);
        u64 o2 = shfl_xor_u64(t2, mk), o3 = shfl_xor_u64(t3, mk);
        ins4(t0, t1, t2, t3, o0);
        ins4(t0, t1, t2, t3, o1);
        ins4(t0, t1, t2, t3, o2);
        ins4(t0, t1, t2, t3, o3);
    }
}

// descending merge of sorted float pairs (a1>=a2), (b1>=b2) -> top-2
__device__ __forceinline__ void merge_desc(float& a1, float& a2, float b1, float b2) {
    float lo = fminf(a1, b1);
    a1 = fmaxf(a1, b1);
    a2 = fmaxf(lo, fmaxf(a2, b2));
}

// ---------------- kernel P: fused prep (x->bf16 | P transpose->bf16 | codes normalize->bf16) ----------------
// grid 4160 x 256: blocks [0,2048) cvt8, [2048,2112) trP, [2112,4160) codes (wave/row).
__global__ __launch_bounds__(256) void k_prep(const float* __restrict__ x,
                                              const float* __restrict__ P,
                                              const float* __restrict__ cb,
                                              ushort_t* __restrict__ xbf,
                                              ushort_t* __restrict__ pbT,
                                              ushort_t* __restrict__ cbf,
                                              u32* __restrict__ count) {
    __shared__ float t[64][65];
    const int b = blockIdx.x;
    const int tid = threadIdx.x;
    if (b == 0 && tid == 0) *count = 0;

    if (b < 2048) {
        // x fp32 -> bf16, 8 elems/thread, 4 grid-stride iters
        const int n8 = 32768 * 512 / 8;
        for (int i = b * 256 + tid; i < n8; i += 2048 * 256) {
            float4 a = ((const float4*)x)[(size_t)i * 2];
            float4 c = ((const float4*)x)[(size_t)i * 2 + 1];
            short8 p;
            p[0] = (short)f2bf(a.x); p[1] = (short)f2bf(a.y);
            p[2] = (short)f2bf(a.z); p[3] = (short)f2bf(a.w);
            p[4] = (short)f2bf(c.x); p[5] = (short)f2bf(c.y);
            p[6] = (short)f2bf(c.z); p[7] = (short)f2bf(c.w);
            ((short8*)xbf)[i] = p;
        }
    } else if (b < 2112) {
        // P [k][n] -> PT [n][k] bf16
        const int bb = b - 2048;
        const int kb = (bb & 7) * 64;
        const int nb = (bb >> 3) * 64;
        const int tx = tid & 63;
        const int ty = tid >> 6;
        #pragma unroll
        for (int r = ty; r < 64; r += 4) t[r][tx] = P[(size_t)(kb + r) * 512 + nb + tx];
        __syncthreads();
        #pragma unroll
        for (int r = ty; r < 64; r += 4)
            pbT[(size_t)(nb + r) * 512 + kb + tx] = f2bf(t[tx][r]);
    } else {
        // codebook row normalize (fp64), one wave per row
        const int row = (b - 2112) * 4 + (tid >> 6);
        const int lane = tid & 63;
        const float* src = cb + (size_t)row * 512 + lane * 8;
        float4 v0 = *(const float4*)src;
        float4 v1 = *(const float4*)(src + 4);
        double s = (double)v0.x * v0.x + (double)v0.y * v0.y + (double)v0.z * v0.z + (double)v0.w * v0.w
                 + (double)v1.x * v1.x + (double)v1.y * v1.y + (double)v1.z * v1.z + (double)v1.w * v1.w;
        #pragma unroll
        for (int mk = 1; mk < 64; mk <<= 1) s += __shfl_xor(s, mk, 64);
        double inv = 1.0 / fmax(sqrt(s), 1e-12);
        short8 o;
        o[0] = (short)f2bf((float)((double)v0.x * inv));
        o[1] = (short)f2bf((float)((double)v0.y * inv));
        o[2] = (short)f2bf((float)((double)v0.z * inv));
        o[3] = (short)f2bf((float)((double)v0.w * inv));
        o[4] = (short)f2bf((float)((double)v1.x * inv));
        o[5] = (short)f2bf((float)((double)v1.y * inv));
        o[6] = (short)f2bf((float)((double)v1.z * inv));
        o[7] = (short)f2bf((float)((double)v1.w * inv));
        *(short8*)(cbf + (size_t)row * 512 + lane * 8) = o;
    }
}

// ---------------- kernel 2: projection GEMM ybf = xbf @ PT^T via MFMA (proven) ----------------
__global__ __launch_bounds__(256) void k_proj(const ushort_t* __restrict__ X,
                                              const ushort_t* __restrict__ PT,
                                              ushort_t* __restrict__ Ybf) {
    __shared__ ushort_t Ab[128 * 64];
    __shared__ ushort_t Bb[128 * 64];
    const int tid = threadIdx.x;
    const int lane = tid & 63;
    const int wid = tid >> 6;
    const int wm = wid & 1, wn = wid >> 1;
    const int rowBase = blockIdx.x * 128;
    const int colBase = blockIdx.y * 128;

    const ushort_t* asrc[4];
    const ushort_t* bsrc[4];
    int ldsoff[4];
    #pragma unroll
    for (int i = 0; i < 4; i++) {
        const int L = i * 256 + tid;
        const int r = L >> 3;
        const int s = (L & 7) ^ (r & 7);
        asrc[i] = X + (size_t)(rowBase + r) * 512 + s * 8;
        bsrc[i] = PT + (size_t)(colBase + r) * 512 + s * 8;
        ldsoff[i] = (i * 256 + (tid & ~63)) * 16;
    }

    f32x4 acc[4][4];
    #pragma unroll
    for (int i = 0; i < 4; i++)
        #pragma unroll
        for (int j = 0; j < 4; j++) {
            f32x4 z = {0.f, 0.f, 0.f, 0.f};
            acc[i][j] = z;
        }

    int aoff[4][2], boff[4][2];
    #pragma unroll
    for (int ti = 0; ti < 4; ti++)
        #pragma unroll
        for (int ks = 0; ks < 2; ks++) {
            const int sa = ks * 4 + (lane >> 4);
            const int ra = wm * 64 + ti * 16 + (lane & 15);
            aoff[ti][ks] = (ra * 8 + (sa ^ (ra & 7))) * 8;
            const int rb = wn * 64 + ti * 16 + (lane & 15);
            boff[ti][ks] = (rb * 8 + (sa ^ (rb & 7))) * 8;
        }

    for (int kt = 0; kt < 512; kt += 64) {
        #pragma unroll
        for (int i = 0; i < 4; i++) {
            __builtin_amdgcn_global_load_lds(
                (const __attribute__((address_space(1))) uint32_t*)(asrc[i] + kt),
                (__attribute__((address_space(3))) uint32_t*)((char*)Ab + ldsoff[i]), 16, 0, 0);
            __builtin_amdgcn_global_load_lds(
                (const __attribute__((address_space(1))) uint32_t*)(bsrc[i] + kt),
                (__attribute__((address_space(3))) uint32_t*)((char*)Bb + ldsoff[i]), 16, 0, 0);
        }
        __syncthreads();
        short8 af[4][2], bfr[4][2];
        #pragma unroll
        for (int ti = 0; ti < 4; ti++)
            #pragma unroll
            for (int ks = 0; ks < 2; ks++) {
                af[ti][ks]  = *(const short8*)(Ab + aoff[ti][ks]);
                bfr[ti][ks] = *(const short8*)(Bb + boff[ti][ks]);
            }
        #pragma unroll
        for (int ks = 0; ks < 2; ks++)
            #pragma unroll
            for (int ti = 0; ti < 4; ti++)
                #pragma unroll
                for (int tj = 0; tj < 4; tj++)
                    acc[ti][tj] = __builtin_amdgcn_mfma_f32_16x16x32_bf16(
                        af[ti][ks], bfr[tj][ks], acc[ti][tj], 0, 0, 0);
        __syncthreads();
    }

    #pragma unroll
    for (int ti = 0; ti < 4; ti++)
        #pragma unroll
        for (int tj = 0; tj < 4; tj++) {
            const int col = colBase + wn * 64 + tj * 16 + (lane & 15);
            #pragma unroll
            for (int reg = 0; reg < 4; reg++) {
                const int row = rowBase + wm * 64 + ti * 16 + (lane >> 4) * 4 + reg;
                Ybf[(size_t)row * 512 + col] = f2bf(acc[ti][tj][reg]);
            }
        }
}

// ---------------- kernel 3: bf16 MFMA GEMM 128x128 (round-9-proven) + XCD-chunked L2 swizzle ----------------
// grid 16384 x 256 (1-D). Decode: xcd = wg&7, idx = wg>>3; mtile = xcd*32 + (idx&31),
// ytile = idx>>5. Each XCD owns a 32-M-tile chunk (A-panels = 4 MB = its L2) and sweeps
// N with M fastest -> A L2-resident after first sweep; B-panel (128 KB) changes per 32 blocks.
// 16384 % 8 == 0 -> the simple xcd-mod decode is bijective (ERRATA #11 safe).
// Compute schedule, staging, epilogue identical to round-9's proven kernel.
__global__ __launch_bounds__(256) void k_gemm(const ushort_t* __restrict__ Y,
                                              const ushort_t* __restrict__ C,
                                              u32* __restrict__ part2) {
    __shared__ ushort_t Ab[128 * 64];
    __shared__ ushort_t Bb[128 * 64];
    __shared__ u32 tmp[128][2][2][2];   // [row][wn][grp][2]
    const int tid = threadIdx.x;
    const int lane = tid & 63;
    const int wid = tid >> 6;
    const int wm = wid & 1, wn = wid >> 1;

    const u32 wg = blockIdx.x;
    const u32 xcd = wg & 7u;
    const u32 idx = wg >> 3;
    const int mtile = (int)(xcd * 32u + (idx & 31u));
    const int ytile = (int)(idx >> 5);
    const int rowBase = mtile * 128;
    const int colBase = ytile * 128;

    const ushort_t* asrc[4];
    const ushort_t* bsrc[4];
    int ldsoff[4];
    #pragma unroll
    for (int i = 0; i < 4; i++) {
        const int L = i * 256 + tid;
        const int r = L >> 3;
        const int s = (L & 7) ^ (r & 7);
        asrc[i] = Y + (size_t)(rowBase + r) * 512 + s * 8;
        bsrc[i] = C + (size_t)(colBase + r) * 512 + s * 8;
        ldsoff[i] = (i * 256 + (tid & ~63)) * 16;
    }

    f32x4 acc[4][4];
    #pragma unroll
    for (int i = 0; i < 4; i++)
        #pragma unroll
        for (int j = 0; j < 4; j++) {
            f32x4 z = {16.f, 16.f, 16.f, 16.f};
            acc[i][j] = z;
        }

    int aoff[4][2], boff[4][2];
    #pragma unroll
    for (int ti = 0; ti < 4; ti++)
        #pragma unroll
        for (int ks = 0; ks < 2; ks++) {
            const int sa = ks * 4 + (lane >> 4);
            const int ra = wm * 64 + ti * 16 + (lane & 15);
            aoff[ti][ks] = (ra * 8 + (sa ^ (ra & 7))) * 8;
            const int rb = wn * 64 + ti * 16 + (lane & 15);
            boff[ti][ks] = (rb * 8 + (sa ^ (rb & 7))) * 8;
        }

    u32 ecol[4];
    #pragma unroll
    for (int tj = 0; tj < 4; tj++) ecol[tj] = 127u - (u32)(wn * 64 + tj * 16 + (lane & 15));

    for (int kt = 0; kt < 512; kt += 64) {
        #pragma unroll
        for (int i = 0; i < 4; i++) {
            __builtin_amdgcn_global_load_lds(
                (const __attribute__((address_space(1))) uint32_t*)(asrc[i] + kt),
                (__attribute__((address_space(3))) uint32_t*)((char*)Ab + ldsoff[i]), 16, 0, 0);
            __builtin_amdgcn_global_load_lds(
                (const __attribute__((address_space(1))) uint32_t*)(bsrc[i] + kt),
                (__attribute__((address_space(3))) uint32_t*)((char*)Bb + ldsoff[i]), 16, 0, 0);
        }
        __syncthreads();
        short8 af[4][2], bfr[4][2];
        #pragma unroll
        for (int ti = 0; ti < 4; ti++)
            #pragma unroll
            for (int ks = 0; ks < 2; ks++) {
                af[ti][ks]  = *(const short8*)(Ab + aoff[ti][ks]);
                bfr[ti][ks] = *(const short8*)(Bb + boff[ti][ks]);
            }
        #pragma unroll
        for (int ks = 0; ks < 2; ks++)
            #pragma unroll
            for (int ti = 0; ti < 4; ti++)
                #pragma unroll
                for (int tj = 0; tj < 4; tj++)
                    acc[ti][tj] = __builtin_amdgcn_mfma_f32_16x16x32_bf16(
                        af[ti][ks], bfr[tj][ks], acc[ti][tj], 0, 0, 0);
        __syncthreads();
    }

    // epilogue: embed col, per-thread top-2 of 4 cols, 3-step butterfly (8-lane groups)
    #pragma unroll
    for (int ti = 0; ti < 4; ti++)
        #pragma unroll
        for (int reg = 0; reg < 4; reg++) {
            float v0 = __uint_as_float((__float_as_uint(acc[ti][0][reg]) & 0xFFFFFF80u) | ecol[0]);
            float v1 = __uint_as_float((__float_as_uint(acc[ti][1][reg]) & 0xFFFFFF80u) | ecol[1]);
            float v2 = __uint_as_float((__float_as_uint(acc[ti][2][reg]) & 0xFFFFFF80u) | ecol[2]);
            float v3 = __uint_as_float((__float_as_uint(acc[ti][3][reg]) & 0xFFFFFF80u) | ecol[3]);
            float m1 = fmaxf(v0, v1);
            float m2 = fminf(v0, v1);
            float med = __builtin_amdgcn_fmed3f(m1, v2, v3);
            m1 = fmaxf(m1, fmaxf(v2, v3));
            m2 = fmaxf(m2, med);
            #pragma unroll
            for (int mk = 1; mk < 8; mk <<= 1) {
                float o1 = __shfl_xor(m1, mk, 64);
                float o2 = __shfl_xor(m2, mk, 64);
                merge_desc(m1, m2, o1, o2);
            }
            if ((lane & 7) == 0) {
                const int mrow = wm * 64 + ti * 16 + (lane >> 4) * 4 + reg;
                const int grp = (lane >> 3) & 1;
                tmp[mrow][wn][grp][0] = __float_as_uint(m1);
                tmp[mrow][wn][grp][1] = __float_as_uint(m2);
            }
        }
    __syncthreads();
    if (tid < 128) {
        float a1 = __uint_as_float(tmp[tid][0][0][0]), a2 = __uint_as_float(tmp[tid][0][0][1]);
        merge_desc(a1, a2, __uint_as_float(tmp[tid][0][1][0]), __uint_as_float(tmp[tid][0][1][1]));
        merge_desc(a1, a2, __uint_as_float(tmp[tid][1][0][0]), __uint_as_float(tmp[tid][1][0][1]));
        merge_desc(a1, a2, __uint_as_float(tmp[tid][1][1][0]), __uint_as_float(tmp[tid][1][1][1]));
        u32* dst = part2 + ((size_t)(rowBase + tid) * 64 + ytile) * 2;
        dst[0] = __float_as_uint(a1);
        dst[1] = __float_as_uint(a2);
    }
}

// ---------------- kernel 4: float-domain winner + margin flag (round-6-proven threshold) ----------------
// grid 8192 x 256 (wave per row).
__global__ __launch_bounds__(256) void k_pick(const u32* __restrict__ part2,
                                              const int* __restrict__ mask,
                                              int* __restrict__ out,
                                              u32* __restrict__ wl,
                                              u32* __restrict__ count) {
    const int row = blockIdx.x * 4 + (threadIdx.x >> 6);
    const int lane = threadIdx.x & 63;
    const u32* base = part2 + (size_t)row * 128;
    const u32 b0 = base[lane];
    const u32 b1 = base[64 + lane];
    // all keys are positive floats -> u32 order == float order
    float a1 = __uint_as_float(b0 > b1 ? b0 : b1);
    float a2 = __uint_as_float(b0 > b1 ? b1 : b0);
    #pragma unroll
    for (int mk = 1; mk < 64; mk <<= 1) {
        float o1 = __shfl_xor(a1, mk, 64);
        float o2 = __shfl_xor(a2, mk, 64);
        merge_desc(a1, a2, o1, o2);
    }
    // decode winner's global col: min col among keys bit-equal to the max
    const u32 w1 = __float_as_uint(a1);
    u32 c0 = (b0 == w1) ? ((u32)(lane >> 1) * 128u + (127u - (b0 & 0x7Fu))) : 0xFFFFu;
    u32 c1 = (b1 == w1) ? ((u32)((64 + lane) >> 1) * 128u + (127u - (b1 & 0x7Fu))) : 0xFFFFu;
    u32 cmin = c0 < c1 ? c0 : c1;
    #pragma unroll
    for (int mk = 1; mk < 64; mk <<= 1) {
        u32 oc = __shfl_xor(cmin, mk, 64);
        cmin = cmin < oc ? cmin : oc;
    }
    if (lane == 0) {
        out[row] = mask[row] ? (int)cmin : 0;
        // margin noise sigma ~= 2.3e-3 (bf16 operands, ||y||~22.6); round-6-proven
        // threshold = 0.006*|score| + 0.002 ~= 10 sigma at typical score 3.7.
        const float s1 = a1 - 16.0f;
        if (a1 - a2 < 0.006f * fabsf(s1) + 0.002f) {
            u32 pos = atomicAdd(count, 1u);
            wl[pos] = (u32)row;
        }
    }
}

// ---------------- kernel 5: exact fp64 fix; extracts its own top-8 from part2 ----------------
// grid 256 x 256, grid-stride over worklist; 16 rows/block.
__global__ __launch_bounds__(256) void k_fix16(const float* __restrict__ x,
                                               const float* __restrict__ P,
                                               const float* __restrict__ cb,
                                               const u32* __restrict__ part2,
                                               const u32* __restrict__ wl,
                                               const u32* __restrict__ count,
                                               const int* __restrict__ mask,
                                               int* __restrict__ out) {
    __shared__ float xs[16][512];
    __shared__ u32 cands_s[16][8];
    __shared__ double nrmw[4][16];
    __shared__ double invn[16];
    __shared__ double wredD[4][8];
    __shared__ double wredC[4][8];
    __shared__ int bestIdx[16];
    const int tid = threadIdx.x;
    const int lane = tid & 63;
    const int wv = tid >> 6;
    const u32 n = *count;

    for (u32 basei = (u32)blockIdx.x * 16u; basei < n; basei += (u32)gridDim.x * 16u) {
        const int nr = (int)((n - basei < 16u) ? (n - basei) : 16u);
        __syncthreads();

        // stage x rows
        {
            const int r = tid >> 4;
            const int rc = r < nr ? r : nr - 1;
            const u32 ridx = wl[basei + rc];
            const float4* src = (const float4*)(x + (size_t)ridx * 512);
            float4* dst = (float4*)&xs[r][0];
            const int c = tid & 15;
            #pragma unroll
            for (int j = 0; j < 8; j++) dst[c + j * 16] = src[c + j * 16];
        }
        // extract top-8 candidates per row from part2 (u64 keys, exact order + col tiebreak)
        for (int rr = wv; rr < 16; rr += 4) {
            const int rc = rr < nr ? rr : nr - 1;
            const u32 rowi = wl[basei + rc];
            const u32* base = part2 + (size_t)rowi * 128;
            const u32 b0 = base[lane];
            const u32 b1 = base[64 + lane];
            const u32 sc0 = b0 & 0xFFFFFF80u;
            const u32 sc1 = b1 & 0xFFFFFF80u;
            const u32 col0 = (u32)(lane >> 1) * 128u + (127u - (b0 & 0x7Fu));
            const u32 col1 = (u32)((64 + lane) >> 1) * 128u + (127u - (b1 & 0x7Fu));
            const u64 k0 = ((u64)(~sc0) << 13) | col0;
            const u64 k1 = ((u64)(~sc1) << 13) | col1;
            u64 t0 = k0 < k1 ? k0 : k1;
            u64 t1 = k0 < k1 ? k1 : k0;
            u64 t2 = ~0ull, t3 = ~0ull;
            butterfly4(t0, t1, t2, t3);
            const u64 g0 = t0, g1 = t1, g2 = t2, g3 = t3;
            u64 e0 = (k0 == g0 || k0 == g1 || k0 == g2 || k0 == g3) ? ~0ull : k0;
            u64 e1 = (k1 == g0 || k1 == g1 || k1 == g2 || k1 == g3) ? ~0ull : k1;
            u64 u0 = e0 < e1 ? e0 : e1;
            u64 u1 = e0 < e1 ? e1 : e0;
            u64 u2 = ~0ull, u3 = ~0ull;
            butterfly4(u0, u1, u2, u3);
            if (lane == 0) {
                cands_s[rr][0] = (u32)(g0 & 0x1FFFu); cands_s[rr][1] = (u32)(g1 & 0x1FFFu);
                cands_s[rr][2] = (u32)(g2 & 0x1FFFu); cands_s[rr][3] = (u32)(g3 & 0x1FFFu);
                cands_s[rr][4] = (u32)(u0 & 0x1FFFu); cands_s[rr][5] = (u32)(u1 & 0x1FFFu);
                cands_s[rr][6] = (u32)(u2 & 0x1FFFu); cands_s[rr][7] = (u32)(u3 & 0x1FFFu);
            }
        }
        __syncthreads();

        // fp64 projection: thread owns columns d0, d0+1 for all 16 rows
        const int d0 = tid * 2;
        double acc[16][2];
        #pragma unroll
        for (int r = 0; r < 16; r++) { acc[r][0] = 0.0; acc[r][1] = 0.0; }
        const float* pp = P + d0;
        for (int k = 0; k < 512; k += 2) {
            float2 pa = *(const float2*)(pp + (size_t)k * 512);
            float2 pb = *(const float2*)(pp + (size_t)(k + 1) * 512);
            const double pa0 = (double)pa.x, pa1 = (double)pa.y;
            const double pb0 = (double)pb.x, pb1 = (double)pb.y;
            #pragma unroll
            for (int r = 0; r < 16; r++) {
                float2 xv = *(const float2*)&xs[r][k];
                const double x0 = (double)xv.x, x1 = (double)xv.y;
                acc[r][0] = fma(x0, pa0, acc[r][0]);
                acc[r][1] = fma(x0, pa1, acc[r][1]);
                acc[r][0] = fma(x1, pb0, acc[r][0]);
                acc[r][1] = fma(x1, pb1, acc[r][1]);
            }
        }

        // fp64 row norms
        #pragma unroll
        for (int r = 0; r < 16; r++) {
            double s = fma(acc[r][0], acc[r][0], acc[r][1] * acc[r][1]);
            #pragma unroll
            for (int mk = 1; mk < 64; mk <<= 1) s += __shfl_xor(s, mk, 64);
            if (lane == 0) nrmw[wv][r] = s;
        }
        __syncthreads();
        if (tid < 16) {
            double t = nrmw[0][tid] + nrmw[1][tid] + nrmw[2][tid] + nrmw[3][tid];
            invn[tid] = 1.0 / fmax(sqrt(t), 1e-12);
        }
        __syncthreads();

        // rescore 8 candidates per row in fp64 from raw codebooks
        for (int r = 0; r < nr; r++) {
            const double xinv = invn[r];
            const double xn0 = acc[r][0] * xinv;
            const double xn1 = acc[r][1] * xinv;
            int vidx[8];
            double pd[8], pc[8];
            #pragma unroll
            for (int c = 0; c < 8; c++) {
                vidx[c] = (int)cands_s[r][c];
                float2 cv = *(const float2*)(cb + (size_t)vidx[c] * 512 + d0);
                const double c0 = (double)cv.x, c1 = (double)cv.y;
                pd[c] = fma(c0, xn0, c1 * xn1);
                pc[c] = fma(c0, c0, c1 * c1);
            }
            #pragma unroll
            for (int mk = 1; mk < 64; mk <<= 1) {
                #pragma unroll
                for (int c = 0; c < 8; c++) {
                    pd[c] += __shfl_xor(pd[c], mk, 64);
                    pc[c] += __shfl_xor(pc[c], mk, 64);
                }
            }
            if (lane == 0) {
                #pragma unroll
                for (int c = 0; c < 8; c++) { wredD[wv][c] = pd[c]; wredC[wv][c] = pc[c]; }
            }
            __syncthreads();
            if (tid == 0) {
                double bs = -1.0e300;
                int bi = 0x7fffffff;
                #pragma unroll
                for (int c = 0; c < 8; c++) {
                    const double D = wredD[0][c] + wredD[1][c] + wredD[2][c] + wredD[3][c];
                    const double Cw = wredC[0][c] + wredC[1][c] + wredC[2][c] + wredC[3][c];
                    const double s = D / fmax(sqrt(Cw), 1e-12);
                    const int v = vidx[c];
                    if (s > bs || (s == bs && v < bi)) { bs = s; bi = v; }
                }
                bestIdx[r] = bi;
            }
            __syncthreads();
        }

        if (tid < nr) {
            const u32 row = wl[basei + tid];
            out[row] = mask[row] ? bestIdx[tid] : 0;
        }
    }
}

// ---------------- launcher ----------------
extern "C" void kernel_launch(void* const* d_in, const int* in_sizes, int n_in,
                              void* d_out, int out_size, void* d_ws, size_t ws_size,
                              hipStream_t stream) {
    const float* x = (const float*)d_in[0];               // [32768,512] fp32
    const int* mask = (const int*)d_in[1];                // [32768] bool->int32
    const float* projection = (const float*)d_in[2];      // [512,512] fp32
    const float* codebooks = (const float*)d_in[3];       // [8192,512] fp32
    int* out = (int*)d_out;                               // [32768] int32

    // workspace (~75 MB): xbf dead after k_proj -> part2 aliases it.
    char* ws = (char*)d_ws;
    ushort_t* xbf = (ushort_t*)ws;                         // 32 MB [0,32)
    u32* part2    = (u32*)ws;                              // 16 MB (aliases xbf)
    ushort_t* ybf = (ushort_t*)(ws + (32u << 20));         // 32 MB [32,64)
    ushort_t* cbf = (ushort_t*)(ws + (64u << 20));         // 8 MB  [64,72)
    ushort_t* pbT = (ushort_t*)(ws + (72u << 20));         // 512 KB
    u32* wl       = (u32*)(ws + (73u << 20));              // 128 KB
    u32* count    = (u32*)(ws + (74u << 20));              // 4 B

    k_prep<<<4160, 256, 0, stream>>>(x, projection, codebooks, xbf, pbT, cbf, count);
    k_proj<<<dim3(256, 4), 256, 0, stream>>>(xbf, pbT, ybf);
    k_gemm<<<16384, 256, 0, stream>>>(ybf, cbf, part2);
    k_pick<<<8192, 256, 0, stream>>>(part2, mask, out, wl, count);
    k_fix16<<<256, 256, 0, stream>>>(x, projection, codebooks, part2, wl, count,
                                     mask, out);
}

// Round 13
// 513.356 us; speedup vs baseline: 1.3993x; 1.3037x over previous
//
#include <hip/hip_runtime.h>
#include <hip/hip_bf16.h>
#include <cstdint>
#include <cstddef>

typedef unsigned long long u64;
typedef unsigned int u32;
typedef unsigned short ushort_t;

typedef __attribute__((ext_vector_type(8))) short short8;
typedef __attribute__((ext_vector_type(4))) float f32x4;

// ---------------- utilities ----------------
__device__ __forceinline__ u64 shfl_xor_u64(u64 v, int m) {
    u32 lo = (u32)v;
    u32 hi = (u32)(v >> 32);
    lo = __shfl_xor(lo, m, 64);
    hi = __shfl_xor(hi, m, 64);
    return ((u64)hi << 32) | lo;
}

__device__ __forceinline__ ushort_t f2bf(float f) {
    u32 u = __float_as_uint(f);
    u32 r = (u + 0x7fffu + ((u >> 16) & 1u)) >> 16;
    return (ushort_t)r;
}

// sorted-insert key k into ascending top-4
__device__ __forceinline__ void ins4(u64& t0, u64& t1, u64& t2, u64& t3, u64 k) {
    bool c0 = k < t0, c1 = k < t1, c2 = k < t2, c3 = k < t3;
    t3 = c3 ? (c2 ? t2 : k) : t3;
    t2 = c2 ? (c1 ? t1 : k) : t2;
    t1 = c1 ? (c0 ? t0 : k) : t1;
    t0 = c0 ? k : t0;
}

__device__ __forceinline__ void butterfly4(u64& t0, u64& t1, u64& t2, u64& t3) {
    #pragma unroll
    for (int mk = 1; mk < 64; mk <<= 1) {
        u64 o0 = shfl_xor_u64(t0, mk), o1 = shfl_xor_u64(t1, mk);
        u64 o2 = shfl_xor_u64(t2, mk), o3 = shfl_xor_u64(t3, mk);
        ins4(t0, t1, t2, t3, o0);
        ins4(t0, t1, t2, t3, o1);
        ins4(t0, t1, t2, t3, o2);
        ins4(t0, t1, t2, t3, o3);
    }
}

// descending merge of sorted float pairs (a1>=a2), (b1>=b2) -> top-2
__device__ __forceinline__ void merge_desc(float& a1, float& a2, float b1, float b2) {
    float lo = fminf(a1, b1);
    a1 = fmaxf(a1, b1);
    a2 = fmaxf(lo, fmaxf(a2, b2));
}

// ---------------- kernel P: fused prep (x->bf16 | P transpose->bf16 | codes normalize->bf16) ----------------
// grid 4160 x 256: blocks [0,2048) cvt8, [2048,2112) trP, [2112,4160) codes (wave/row).
__global__ __launch_bounds__(256) void k_prep(const float* __restrict__ x,
                                              const float* __restrict__ P,
                                              const float* __restrict__ cb,
                                              ushort_t* __restrict__ xbf,
                                              ushort_t* __restrict__ pbT,
                                              ushort_t* __restrict__ cbf,
                                              u32* __restrict__ count) {
    __shared__ float t[64][65];
    const int b = blockIdx.x;
    const int tid = threadIdx.x;
    if (b == 0 && tid == 0) *count = 0;

    if (b < 2048) {
        // x fp32 -> bf16, 8 elems/thread, 4 grid-stride iters
        const int n8 = 32768 * 512 / 8;
        for (int i = b * 256 + tid; i < n8; i += 2048 * 256) {
            float4 a = ((const float4*)x)[(size_t)i * 2];
            float4 c = ((const float4*)x)[(size_t)i * 2 + 1];
            short8 p;
            p[0] = (short)f2bf(a.x); p[1] = (short)f2bf(a.y);
            p[2] = (short)f2bf(a.z); p[3] = (short)f2bf(a.w);
            p[4] = (short)f2bf(c.x); p[5] = (short)f2bf(c.y);
            p[6] = (short)f2bf(c.z); p[7] = (short)f2bf(c.w);
            ((short8*)xbf)[i] = p;
        }
    } else if (b < 2112) {
        // P [k][n] -> PT [n][k] bf16
        const int bb = b - 2048;
        const int kb = (bb & 7) * 64;
        const int nb = (bb >> 3) * 64;
        const int tx = tid & 63;
        const int ty = tid >> 6;
        #pragma unroll
        for (int r = ty; r < 64; r += 4) t[r][tx] = P[(size_t)(kb + r) * 512 + nb + tx];
        __syncthreads();
        #pragma unroll
        for (int r = ty; r < 64; r += 4)
            pbT[(size_t)(nb + r) * 512 + kb + tx] = f2bf(t[tx][r]);
    } else {
        // codebook row normalize (fp64), one wave per row
        const int row = (b - 2112) * 4 + (tid >> 6);
        const int lane = tid & 63;
        const float* src = cb + (size_t)row * 512 + lane * 8;
        float4 v0 = *(const float4*)src;
        float4 v1 = *(const float4*)(src + 4);
        double s = (double)v0.x * v0.x + (double)v0.y * v0.y + (double)v0.z * v0.z + (double)v0.w * v0.w
                 + (double)v1.x * v1.x + (double)v1.y * v1.y + (double)v1.z * v1.z + (double)v1.w * v1.w;
        #pragma unroll
        for (int mk = 1; mk < 64; mk <<= 1) s += __shfl_xor(s, mk, 64);
        double inv = 1.0 / fmax(sqrt(s), 1e-12);
        short8 o;
        o[0] = (short)f2bf((float)((double)v0.x * inv));
        o[1] = (short)f2bf((float)((double)v0.y * inv));
        o[2] = (short)f2bf((float)((double)v0.z * inv));
        o[3] = (short)f2bf((float)((double)v0.w * inv));
        o[4] = (short)f2bf((float)((double)v1.x * inv));
        o[5] = (short)f2bf((float)((double)v1.y * inv));
        o[6] = (short)f2bf((float)((double)v1.z * inv));
        o[7] = (short)f2bf((float)((double)v1.w * inv));
        *(short8*)(cbf + (size_t)row * 512 + lane * 8) = o;
    }
}

// ---------------- kernel 2: projection GEMM ybf = xbf @ PT^T via MFMA (proven) ----------------
__global__ __launch_bounds__(256) void k_proj(const ushort_t* __restrict__ X,
                                              const ushort_t* __restrict__ PT,
                                              ushort_t* __restrict__ Ybf) {
    __shared__ ushort_t Ab[128 * 64];
    __shared__ ushort_t Bb[128 * 64];
    const int tid = threadIdx.x;
    const int lane = tid & 63;
    const int wid = tid >> 6;
    const int wm = wid & 1, wn = wid >> 1;
    const int rowBase = blockIdx.x * 128;
    const int colBase = blockIdx.y * 128;

    const ushort_t* asrc[4];
    const ushort_t* bsrc[4];
    int ldsoff[4];
    #pragma unroll
    for (int i = 0; i < 4; i++) {
        const int L = i * 256 + tid;
        const int r = L >> 3;
        const int s = (L & 7) ^ (r & 7);
        asrc[i] = X + (size_t)(rowBase + r) * 512 + s * 8;
        bsrc[i] = PT + (size_t)(colBase + r) * 512 + s * 8;
        ldsoff[i] = (i * 256 + (tid & ~63)) * 16;
    }

    f32x4 acc[4][4];
    #pragma unroll
    for (int i = 0; i < 4; i++)
        #pragma unroll
        for (int j = 0; j < 4; j++) {
            f32x4 z = {0.f, 0.f, 0.f, 0.f};
            acc[i][j] = z;
        }

    int aoff[4][2], boff[4][2];
    #pragma unroll
    for (int ti = 0; ti < 4; ti++)
        #pragma unroll
        for (int ks = 0; ks < 2; ks++) {
            const int sa = ks * 4 + (lane >> 4);
            const int ra = wm * 64 + ti * 16 + (lane & 15);
            aoff[ti][ks] = (ra * 8 + (sa ^ (ra & 7))) * 8;
            const int rb = wn * 64 + ti * 16 + (lane & 15);
            boff[ti][ks] = (rb * 8 + (sa ^ (rb & 7))) * 8;
        }

    for (int kt = 0; kt < 512; kt += 64) {
        #pragma unroll
        for (int i = 0; i < 4; i++) {
            __builtin_amdgcn_global_load_lds(
                (const __attribute__((address_space(1))) uint32_t*)(asrc[i] + kt),
                (__attribute__((address_space(3))) uint32_t*)((char*)Ab + ldsoff[i]), 16, 0, 0);
            __builtin_amdgcn_global_load_lds(
                (const __attribute__((address_space(1))) uint32_t*)(bsrc[i] + kt),
                (__attribute__((address_space(3))) uint32_t*)((char*)Bb + ldsoff[i]), 16, 0, 0);
        }
        __syncthreads();
        short8 af[4][2], bfr[4][2];
        #pragma unroll
        for (int ti = 0; ti < 4; ti++)
            #pragma unroll
            for (int ks = 0; ks < 2; ks++) {
                af[ti][ks]  = *(const short8*)(Ab + aoff[ti][ks]);
                bfr[ti][ks] = *(const short8*)(Bb + boff[ti][ks]);
            }
        #pragma unroll
        for (int ks = 0; ks < 2; ks++)
            #pragma unroll
            for (int ti = 0; ti < 4; ti++)
                #pragma unroll
                for (int tj = 0; tj < 4; tj++)
                    acc[ti][tj] = __builtin_amdgcn_mfma_f32_16x16x32_bf16(
                        af[ti][ks], bfr[tj][ks], acc[ti][tj], 0, 0, 0);
        __syncthreads();
    }

    #pragma unroll
    for (int ti = 0; ti < 4; ti++)
        #pragma unroll
        for (int tj = 0; tj < 4; tj++) {
            const int col = colBase + wn * 64 + tj * 16 + (lane & 15);
            #pragma unroll
            for (int reg = 0; reg < 4; reg++) {
                const int row = rowBase + wm * 64 + ti * 16 + (lane >> 4) * 4 + reg;
                Ybf[(size_t)row * 512 + col] = f2bf(acc[ti][tj][reg]);
            }
        }
}

// ---------------- kernel 3: bf16 MFMA GEMM 128x128 (round-9-proven) + XCD-chunked L2 swizzle ----------------
// grid 16384 x 256 (1-D). Decode: xcd = wg&7, idx = wg>>3; mtile = xcd*32 + (idx&31),
// ytile = idx>>5. 16384 % 8 == 0 -> bijective (ERRATA #11 safe). Neutral-to-slightly-positive
// vs round-9 linear decode (348 vs 356 us); kept for free locality.
__global__ __launch_bounds__(256) void k_gemm(const ushort_t* __restrict__ Y,
                                              const ushort_t* __restrict__ C,
                                              u32* __restrict__ part2) {
    __shared__ ushort_t Ab[128 * 64];
    __shared__ ushort_t Bb[128 * 64];
    __shared__ u32 tmp[128][2][2][2];   // [row][wn][grp][2]
    const int tid = threadIdx.x;
    const int lane = tid & 63;
    const int wid = tid >> 6;
    const int wm = wid & 1, wn = wid >> 1;

    const u32 wg = blockIdx.x;
    const u32 xcd = wg & 7u;
    const u32 idx = wg >> 3;
    const int mtile = (int)(xcd * 32u + (idx & 31u));
    const int ytile = (int)(idx >> 5);
    const int rowBase = mtile * 128;
    const int colBase = ytile * 128;

    const ushort_t* asrc[4];
    const ushort_t* bsrc[4];
    int ldsoff[4];
    #pragma unroll
    for (int i = 0; i < 4; i++) {
        const int L = i * 256 + tid;
        const int r = L >> 3;
        const int s = (L & 7) ^ (r & 7);
        asrc[i] = Y + (size_t)(rowBase + r) * 512 + s * 8;
        bsrc[i] = C + (size_t)(colBase + r) * 512 + s * 8;
        ldsoff[i] = (i * 256 + (tid & ~63)) * 16;
    }

    f32x4 acc[4][4];
    #pragma unroll
    for (int i = 0; i < 4; i++)
        #pragma unroll
        for (int j = 0; j < 4; j++) {
            f32x4 z = {16.f, 16.f, 16.f, 16.f};
            acc[i][j] = z;
        }

    int aoff[4][2], boff[4][2];
    #pragma unroll
    for (int ti = 0; ti < 4; ti++)
        #pragma unroll
        for (int ks = 0; ks < 2; ks++) {
            const int sa = ks * 4 + (lane >> 4);
            const int ra = wm * 64 + ti * 16 + (lane & 15);
            aoff[ti][ks] = (ra * 8 + (sa ^ (ra & 7))) * 8;
            const int rb = wn * 64 + ti * 16 + (lane & 15);
            boff[ti][ks] = (rb * 8 + (sa ^ (rb & 7))) * 8;
        }

    u32 ecol[4];
    #pragma unroll
    for (int tj = 0; tj < 4; tj++) ecol[tj] = 127u - (u32)(wn * 64 + tj * 16 + (lane & 15));

    for (int kt = 0; kt < 512; kt += 64) {
        #pragma unroll
        for (int i = 0; i < 4; i++) {
            __builtin_amdgcn_global_load_lds(
                (const __attribute__((address_space(1))) uint32_t*)(asrc[i] + kt),
                (__attribute__((address_space(3))) uint32_t*)((char*)Ab + ldsoff[i]), 16, 0, 0);
            __builtin_amdgcn_global_load_lds(
                (const __attribute__((address_space(1))) uint32_t*)(bsrc[i] + kt),
                (__attribute__((address_space(3))) uint32_t*)((char*)Bb + ldsoff[i]), 16, 0, 0);
        }
        __syncthreads();
        short8 af[4][2], bfr[4][2];
        #pragma unroll
        for (int ti = 0; ti < 4; ti++)
            #pragma unroll
            for (int ks = 0; ks < 2; ks++) {
                af[ti][ks]  = *(const short8*)(Ab + aoff[ti][ks]);
                bfr[ti][ks] = *(const short8*)(Bb + boff[ti][ks]);
            }
        #pragma unroll
        for (int ks = 0; ks < 2; ks++)
            #pragma unroll
            for (int ti = 0; ti < 4; ti++)
                #pragma unroll
                for (int tj = 0; tj < 4; tj++)
                    acc[ti][tj] = __builtin_amdgcn_mfma_f32_16x16x32_bf16(
                        af[ti][ks], bfr[tj][ks], acc[ti][tj], 0, 0, 0);
        __syncthreads();
    }

    // epilogue: embed col, per-thread top-2 of 4 cols, 3-step butterfly (8-lane groups)
    #pragma unroll
    for (int ti = 0; ti < 4; ti++)
        #pragma unroll
        for (int reg = 0; reg < 4; reg++) {
            float v0 = __uint_as_float((__float_as_uint(acc[ti][0][reg]) & 0xFFFFFF80u) | ecol[0]);
            float v1 = __uint_as_float((__float_as_uint(acc[ti][1][reg]) & 0xFFFFFF80u) | ecol[1]);
            float v2 = __uint_as_float((__float_as_uint(acc[ti][2][reg]) & 0xFFFFFF80u) | ecol[2]);
            float v3 = __uint_as_float((__float_as_uint(acc[ti][3][reg]) & 0xFFFFFF80u) | ecol[3]);
            float m1 = fmaxf(v0, v1);
            float m2 = fminf(v0, v1);
            float med = __builtin_amdgcn_fmed3f(m1, v2, v3);
            m1 = fmaxf(m1, fmaxf(v2, v3));
            m2 = fmaxf(m2, med);
            #pragma unroll
            for (int mk = 1; mk < 8; mk <<= 1) {
                float o1 = __shfl_xor(m1, mk, 64);
                float o2 = __shfl_xor(m2, mk, 64);
                merge_desc(m1, m2, o1, o2);
            }
            if ((lane & 7) == 0) {
                const int mrow = wm * 64 + ti * 16 + (lane >> 4) * 4 + reg;
                const int grp = (lane >> 3) & 1;
                tmp[mrow][wn][grp][0] = __float_as_uint(m1);
                tmp[mrow][wn][grp][1] = __float_as_uint(m2);
            }
        }
    __syncthreads();
    if (tid < 128) {
        float a1 = __uint_as_float(tmp[tid][0][0][0]), a2 = __uint_as_float(tmp[tid][0][0][1]);
        merge_desc(a1, a2, __uint_as_float(tmp[tid][0][1][0]), __uint_as_float(tmp[tid][0][1][1]));
        merge_desc(a1, a2, __uint_as_float(tmp[tid][1][0][0]), __uint_as_float(tmp[tid][1][0][1]));
        merge_desc(a1, a2, __uint_as_float(tmp[tid][1][1][0]), __uint_as_float(tmp[tid][1][1][1]));
        u32* dst = part2 + ((size_t)(rowBase + tid) * 64 + ytile) * 2;
        dst[0] = __float_as_uint(a1);
        dst[1] = __float_as_uint(a2);
    }
}

// ---------------- kernel 4: float-domain winner + margin flag (round-6-proven threshold) ----------------
// grid 8192 x 256 (wave per row).
__global__ __launch_bounds__(256) void k_pick(const u32* __restrict__ part2,
                                              const int* __restrict__ mask,
                                              int* __restrict__ out,
                                              u32* __restrict__ wl,
                                              u32* __restrict__ count) {
    const int row = blockIdx.x * 4 + (threadIdx.x >> 6);
    const int lane = threadIdx.x & 63;
    const u32* base = part2 + (size_t)row * 128;
    const u32 b0 = base[lane];
    const u32 b1 = base[64 + lane];
    // all keys are positive floats -> u32 order == float order
    float a1 = __uint_as_float(b0 > b1 ? b0 : b1);
    float a2 = __uint_as_float(b0 > b1 ? b1 : b0);
    #pragma unroll
    for (int mk = 1; mk < 64; mk <<= 1) {
        float o1 = __shfl_xor(a1, mk, 64);
        float o2 = __shfl_xor(a2, mk, 64);
        merge_desc(a1, a2, o1, o2);
    }
    // decode winner's global col: min col among keys bit-equal to the max
    const u32 w1 = __float_as_uint(a1);
    u32 c0 = (b0 == w1) ? ((u32)(lane >> 1) * 128u + (127u - (b0 & 0x7Fu))) : 0xFFFFu;
    u32 c1 = (b1 == w1) ? ((u32)((64 + lane) >> 1) * 128u + (127u - (b1 & 0x7Fu))) : 0xFFFFu;
    u32 cmin = c0 < c1 ? c0 : c1;
    #pragma unroll
    for (int mk = 1; mk < 64; mk <<= 1) {
        u32 oc = __shfl_xor(cmin, mk, 64);
        cmin = cmin < oc ? cmin : oc;
    }
    if (lane == 0) {
        out[row] = mask[row] ? (int)cmin : 0;
        // margin noise sigma ~= 2.3e-3 (bf16 operands, ||y||~22.6); round-6-proven
        // threshold = 0.006*|score| + 0.002 ~= 10 sigma at typical score 3.7.
        const float s1 = a1 - 16.0f;
        if (a1 - a2 < 0.006f * fabsf(s1) + 0.002f) {
            u32 pos = atomicAdd(count, 1u);
            wl[pos] = (u32)row;
        }
    }
}

// ---------------- kernel 5: exact fp64 fix, 4 rows/block (parallelism fix) ----------------
// grid 1024 x 256, grid-stride over worklist; 4 rows/block (one wave per row for staging
// and candidate extraction; fp64 projection cooperative across all 256 threads).
// Math identical to the proven 16-row version; only the block decomposition changed.
__global__ __launch_bounds__(256) void k_fix4(const float* __restrict__ x,
                                              const float* __restrict__ P,
                                              const float* __restrict__ cb,
                                              const u32* __restrict__ part2,
                                              const u32* __restrict__ wl,
                                              const u32* __restrict__ count,
                                              const int* __restrict__ mask,
                                              int* __restrict__ out) {
    __shared__ float xs[4][512];
    __shared__ u32 cands_s[4][8];
    __shared__ double nrmw[4][4];
    __shared__ double invn[4];
    __shared__ double wredD[4][8];
    __shared__ double wredC[4][8];
    __shared__ int bestIdx[4];
    const int tid = threadIdx.x;
    const int lane = tid & 63;
    const int wv = tid >> 6;
    const u32 n = *count;

    for (u32 basei = (u32)blockIdx.x * 4u; basei < n; basei += (u32)gridDim.x * 4u) {
        const int nr = (int)((n - basei < 4u) ? (n - basei) : 4u);
        __syncthreads();

        // stage x rows: wave wv stages row wv (clamped)
        {
            const int rc = wv < nr ? wv : nr - 1;
            const u32 ridx = wl[basei + rc];
            const float4* src = (const float4*)(x + (size_t)ridx * 512);
            float4* dst = (float4*)&xs[wv][0];
            dst[lane] = src[lane];
            dst[lane + 64] = src[lane + 64];
        }
        // extract top-8 candidates: wave wv handles row wv
        {
            const int rc = wv < nr ? wv : nr - 1;
            const u32 rowi = wl[basei + rc];
            const u32* base = part2 + (size_t)rowi * 128;
            const u32 b0 = base[lane];
            const u32 b1 = base[64 + lane];
            const u32 sc0 = b0 & 0xFFFFFF80u;
            const u32 sc1 = b1 & 0xFFFFFF80u;
            const u32 col0 = (u32)(lane >> 1) * 128u + (127u - (b0 & 0x7Fu));
            const u32 col1 = (u32)((64 + lane) >> 1) * 128u + (127u - (b1 & 0x7Fu));
            const u64 k0 = ((u64)(~sc0) << 13) | col0;
            const u64 k1 = ((u64)(~sc1) << 13) | col1;
            u64 t0 = k0 < k1 ? k0 : k1;
            u64 t1 = k0 < k1 ? k1 : k0;
            u64 t2 = ~0ull, t3 = ~0ull;
            butterfly4(t0, t1, t2, t3);
            const u64 g0 = t0, g1 = t1, g2 = t2, g3 = t3;
            u64 e0 = (k0 == g0 || k0 == g1 || k0 == g2 || k0 == g3) ? ~0ull : k0;
            u64 e1 = (k1 == g0 || k1 == g1 || k1 == g2 || k1 == g3) ? ~0ull : k1;
            u64 u0 = e0 < e1 ? e0 : e1;
            u64 u1 = e0 < e1 ? e1 : e0;
            u64 u2 = ~0ull, u3 = ~0ull;
            butterfly4(u0, u1, u2, u3);
            if (lane == 0) {
                cands_s[wv][0] = (u32)(g0 & 0x1FFFu); cands_s[wv][1] = (u32)(g1 & 0x1FFFu);
                cands_s[wv][2] = (u32)(g2 & 0x1FFFu); cands_s[wv][3] = (u32)(g3 & 0x1FFFu);
                cands_s[wv][4] = (u32)(u0 & 0x1FFFu); cands_s[wv][5] = (u32)(u1 & 0x1FFFu);
                cands_s[wv][6] = (u32)(u2 & 0x1FFFu); cands_s[wv][7] = (u32)(u3 & 0x1FFFu);
            }
        }
        __syncthreads();

        // fp64 projection: thread owns columns d0, d0+1 for all 4 rows
        const int d0 = tid * 2;
        double acc[4][2];
        #pragma unroll
        for (int r = 0; r < 4; r++) { acc[r][0] = 0.0; acc[r][1] = 0.0; }
        const float* pp = P + d0;
        for (int k = 0; k < 512; k += 2) {
            float2 pa = *(const float2*)(pp + (size_t)k * 512);
            float2 pb = *(const float2*)(pp + (size_t)(k + 1) * 512);
            const double pa0 = (double)pa.x, pa1 = (double)pa.y;
            const double pb0 = (double)pb.x, pb1 = (double)pb.y;
            #pragma unroll
            for (int r = 0; r < 4; r++) {
                float2 xv = *(const float2*)&xs[r][k];
                const double x0 = (double)xv.x, x1 = (double)xv.y;
                acc[r][0] = fma(x0, pa0, acc[r][0]);
                acc[r][1] = fma(x0, pa1, acc[r][1]);
                acc[r][0] = fma(x1, pb0, acc[r][0]);
                acc[r][1] = fma(x1, pb1, acc[r][1]);
            }
        }

        // fp64 row norms
        #pragma unroll
        for (int r = 0; r < 4; r++) {
            double s = fma(acc[r][0], acc[r][0], acc[r][1] * acc[r][1]);
            #pragma unroll
            for (int mk = 1; mk < 64; mk <<= 1) s += __shfl_xor(s, mk, 64);
            if (lane == 0) nrmw[wv][r] = s;
        }
        __syncthreads();
        if (tid < 4) {
            double t = nrmw[0][tid] + nrmw[1][tid] + nrmw[2][tid] + nrmw[3][tid];
            invn[tid] = 1.0 / fmax(sqrt(t), 1e-12);
        }
        __syncthreads();

        // rescore 8 candidates per row in fp64 from raw codebooks
        for (int r = 0; r < nr; r++) {
            const double xinv = invn[r];
            const double xn0 = acc[r][0] * xinv;
            const double xn1 = acc[r][1] * xinv;
            int vidx[8];
            double pd[8], pc[8];
            #pragma unroll
            for (int c = 0; c < 8; c++) {
                vidx[c] = (int)cands_s[r][c];
                float2 cv = *(const float2*)(cb + (size_t)vidx[c] * 512 + d0);
                const double c0 = (double)cv.x, c1 = (double)cv.y;
                pd[c] = fma(c0, xn0, c1 * xn1);
                pc[c] = fma(c0, c0, c1 * c1);
            }
            #pragma unroll
            for (int mk = 1; mk < 64; mk <<= 1) {
                #pragma unroll
                for (int c = 0; c < 8; c++) {
                    pd[c] += __shfl_xor(pd[c], mk, 64);
                    pc[c] += __shfl_xor(pc[c], mk, 64);
                }
            }
            if (lane == 0) {
                #pragma unroll
                for (int c = 0; c < 8; c++) { wredD[wv][c] = pd[c]; wredC[wv][c] = pc[c]; }
            }
            __syncthreads();
            if (tid == 0) {
                double bs = -1.0e300;
                int bi = 0x7fffffff;
                #pragma unroll
                for (int c = 0; c < 8; c++) {
                    const double D = wredD[0][c] + wredD[1][c] + wredD[2][c] + wredD[3][c];
                    const double Cw = wredC[0][c] + wredC[1][c] + wredC[2][c] + wredC[3][c];
                    const double s = D / fmax(sqrt(Cw), 1e-12);
                    const int v = vidx[c];
                    if (s > bs || (s == bs && v < bi)) { bs = s; bi = v; }
                }
                bestIdx[r] = bi;
            }
            __syncthreads();
        }

        if (tid < nr) {
            const u32 row = wl[basei + tid];
            out[row] = mask[row] ? bestIdx[tid] : 0;
        }
    }
}

// ---------------- launcher ----------------
extern "C" void kernel_launch(void* const* d_in, const int* in_sizes, int n_in,
                              void* d_out, int out_size, void* d_ws, size_t ws_size,
                              hipStream_t stream) {
    const float* x = (const float*)d_in[0];               // [32768,512] fp32
    const int* mask = (const int*)d_in[1];                // [32768] bool->int32
    const float* projection = (const float*)d_in[2];      // [512,512] fp32
    const float* codebooks = (const float*)d_in[3];       // [8192,512] fp32
    int* out = (int*)d_out;                               // [32768] int32

    // workspace (~75 MB): xbf dead after k_proj -> part2 aliases it.
    char* ws = (char*)d_ws;
    ushort_t* xbf = (ushort_t*)ws;                         // 32 MB [0,32)
    u32* part2    = (u32*)ws;                              // 16 MB (aliases xbf)
    ushort_t* ybf = (ushort_t*)(ws + (32u << 20));         // 32 MB [32,64)
    ushort_t* cbf = (ushort_t*)(ws + (64u << 20));         // 8 MB  [64,72)
    ushort_t* pbT = (ushort_t*)(ws + (72u << 20));         // 512 KB
    u32* wl       = (u32*)(ws + (73u << 20));              // 128 KB
    u32* count    = (u32*)(ws + (74u << 20));              // 4 B

    k_prep<<<4160, 256, 0, stream>>>(x, projection, codebooks, xbf, pbT, cbf, count);
    k_proj<<<dim3(256, 4), 256, 0, stream>>>(xbf, pbT, ybf);
    k_gemm<<<16384, 256, 0, stream>>>(ybf, cbf, part2);
    k_pick<<<8192, 256, 0, stream>>>(part2, mask, out, wl, count);
    k_fix4<<<1024, 256, 0, stream>>>(x, projection, codebooks, part2, wl, count,
                                     mask, out);
}

// Round 15
// 513.007 us; speedup vs baseline: 1.4003x; 1.0007x over previous
//
#include <hip/hip_runtime.h>
#include <hip/hip_bf16.h>
#include <cstdint>
#include <cstddef>

typedef unsigned long long u64;
typedef unsigned int u32;
typedef unsigned short ushort_t;

typedef __attribute__((ext_vector_type(8))) short short8;
typedef __attribute__((ext_vector_type(4))) float f32x4;

// ---------------- utilities ----------------
__device__ __forceinline__ u64 shfl_xor_u64(u64 v, int m) {
    u32 lo = (u32)v;
    u32 hi = (u32)(v >> 32);
    lo = __shfl_xor(lo, m, 64);
    hi = __shfl_xor(hi, m, 64);
    return ((u64)hi << 32) | lo;
}

__device__ __forceinline__ ushort_t f2bf(float f) {
    u32 u = __float_as_uint(f);
    u32 r = (u + 0x7fffu + ((u >> 16) & 1u)) >> 16;
    return (ushort_t)r;
}

// sorted-insert key k into ascending top-4
__device__ __forceinline__ void ins4(u64& t0, u64& t1, u64& t2, u64& t3, u64 k) {
    bool c0 = k < t0, c1 = k < t1, c2 = k < t2, c3 = k < t3;
    t3 = c3 ? (c2 ? t2 : k) : t3;
    t2 = c2 ? (c1 ? t1 : k) : t2;
    t1 = c1 ? (c0 ? t0 : k) : t1;
    t0 = c0 ? k : t0;
}

__device__ __forceinline__ void butterfly4(u64& t0, u64& t1, u64& t2, u64& t3) {
    #pragma unroll
    for (int mk = 1; mk < 64; mk <<= 1) {
        u64 o0 = shfl_xor_u64(t0, mk), o1 = shfl_xor_u64(t1, mk);
        u64 o2 = shfl_xor_u64(t2, mk), o3 = shfl_xor_u64(t3, mk);
        ins4(t0, t1, t2, t3, o0);
        ins4(t0, t1, t2, t3, o1);
        ins4(t0, t1, t2, t3, o2);
        ins4(t0, t1, t2, t3, o3);
    }
}

// descending merge of sorted float pairs (a1>=a2), (b1>=b2) -> top-2
__device__ __forceinline__ void merge_desc(float& a1, float& a2, float b1, float b2) {
    float lo = fminf(a1, b1);
    a1 = fmaxf(a1, b1);
    a2 = fmaxf(lo, fmaxf(a2, b2));
}

// ---------------- kernel P: fused prep (x->bf16 | P transpose->bf16 | codes normalize->bf16) ----------------
// grid 4160 x 256: blocks [0,2048) cvt8, [2048,2112) trP, [2112,4160) codes (wave/row).
__global__ __launch_bounds__(256) void k_prep(const float* __restrict__ x,
                                              const float* __restrict__ P,
                                              const float* __restrict__ cb,
                                              ushort_t* __restrict__ xbf,
                                              ushort_t* __restrict__ pbT,
                                              ushort_t* __restrict__ cbf,
                                              u32* __restrict__ count) {
    __shared__ float t[64][65];
    const int b = blockIdx.x;
    const int tid = threadIdx.x;
    if (b == 0 && tid == 0) *count = 0;

    if (b < 2048) {
        // x fp32 -> bf16, 8 elems/thread, 4 grid-stride iters
        const int n8 = 32768 * 512 / 8;
        for (int i = b * 256 + tid; i < n8; i += 2048 * 256) {
            float4 a = ((const float4*)x)[(size_t)i * 2];
            float4 c = ((const float4*)x)[(size_t)i * 2 + 1];
            short8 p;
            p[0] = (short)f2bf(a.x); p[1] = (short)f2bf(a.y);
            p[2] = (short)f2bf(a.z); p[3] = (short)f2bf(a.w);
            p[4] = (short)f2bf(c.x); p[5] = (short)f2bf(c.y);
            p[6] = (short)f2bf(c.z); p[7] = (short)f2bf(c.w);
            ((short8*)xbf)[i] = p;
        }
    } else if (b < 2112) {
        // P [k][n] -> PT [n][k] bf16
        const int bb = b - 2048;
        const int kb = (bb & 7) * 64;
        const int nb = (bb >> 3) * 64;
        const int tx = tid & 63;
        const int ty = tid >> 6;
        #pragma unroll
        for (int r = ty; r < 64; r += 4) t[r][tx] = P[(size_t)(kb + r) * 512 + nb + tx];
        __syncthreads();
        #pragma unroll
        for (int r = ty; r < 64; r += 4)
            pbT[(size_t)(nb + r) * 512 + kb + tx] = f2bf(t[tx][r]);
    } else {
        // codebook row normalize (fp64), one wave per row
        const int row = (b - 2112) * 4 + (tid >> 6);
        const int lane = tid & 63;
        const float* src = cb + (size_t)row * 512 + lane * 8;
        float4 v0 = *(const float4*)src;
        float4 v1 = *(const float4*)(src + 4);
        double s = (double)v0.x * v0.x + (double)v0.y * v0.y + (double)v0.z * v0.z + (double)v0.w * v0.w
                 + (double)v1.x * v1.x + (double)v1.y * v1.y + (double)v1.z * v1.z + (double)v1.w * v1.w;
        #pragma unroll
        for (int mk = 1; mk < 64; mk <<= 1) s += __shfl_xor(s, mk, 64);
        double inv = 1.0 / fmax(sqrt(s), 1e-12);
        short8 o;
        o[0] = (short)f2bf((float)((double)v0.x * inv));
        o[1] = (short)f2bf((float)((double)v0.y * inv));
        o[2] = (short)f2bf((float)((double)v0.z * inv));
        o[3] = (short)f2bf((float)((double)v0.w * inv));
        o[4] = (short)f2bf((float)((double)v1.x * inv));
        o[5] = (short)f2bf((float)((double)v1.y * inv));
        o[6] = (short)f2bf((float)((double)v1.z * inv));
        o[7] = (short)f2bf((float)((double)v1.w * inv));
        *(short8*)(cbf + (size_t)row * 512 + lane * 8) = o;
    }
}

// ---------------- kernel 2: projection GEMM ybf = xbf @ PT^T via MFMA (proven) ----------------
__global__ __launch_bounds__(256) void k_proj(const ushort_t* __restrict__ X,
                                              const ushort_t* __restrict__ PT,
                                              ushort_t* __restrict__ Ybf) {
    __shared__ ushort_t Ab[128 * 64];
    __shared__ ushort_t Bb[128 * 64];
    const int tid = threadIdx.x;
    const int lane = tid & 63;
    const int wid = tid >> 6;
    const int wm = wid & 1, wn = wid >> 1;
    const int rowBase = blockIdx.x * 128;
    const int colBase = blockIdx.y * 128;

    const ushort_t* asrc[4];
    const ushort_t* bsrc[4];
    int ldsoff[4];
    #pragma unroll
    for (int i = 0; i < 4; i++) {
        const int L = i * 256 + tid;
        const int r = L >> 3;
        const int s = (L & 7) ^ (r & 7);
        asrc[i] = X + (size_t)(rowBase + r) * 512 + s * 8;
        bsrc[i] = PT + (size_t)(colBase + r) * 512 + s * 8;
        ldsoff[i] = (i * 256 + (tid & ~63)) * 16;
    }

    f32x4 acc[4][4];
    #pragma unroll
    for (int i = 0; i < 4; i++)
        #pragma unroll
        for (int j = 0; j < 4; j++) {
            f32x4 z = {0.f, 0.f, 0.f, 0.f};
            acc[i][j] = z;
        }

    int aoff[4][2], boff[4][2];
    #pragma unroll
    for (int ti = 0; ti < 4; ti++)
        #pragma unroll
        for (int ks = 0; ks < 2; ks++) {
            const int sa = ks * 4 + (lane >> 4);
            const int ra = wm * 64 + ti * 16 + (lane & 15);
            aoff[ti][ks] = (ra * 8 + (sa ^ (ra & 7))) * 8;
            const int rb = wn * 64 + ti * 16 + (lane & 15);
            boff[ti][ks] = (rb * 8 + (sa ^ (rb & 7))) * 8;
        }

    for (int kt = 0; kt < 512; kt += 64) {
        #pragma unroll
        for (int i = 0; i < 4; i++) {
            __builtin_amdgcn_global_load_lds(
                (const __attribute__((address_space(1))) uint32_t*)(asrc[i] + kt),
                (__attribute__((address_space(3))) uint32_t*)((char*)Ab + ldsoff[i]), 16, 0, 0);
            __builtin_amdgcn_global_load_lds(
                (const __attribute__((address_space(1))) uint32_t*)(bsrc[i] + kt),
                (__attribute__((address_space(3))) uint32_t*)((char*)Bb + ldsoff[i]), 16, 0, 0);
        }
        __syncthreads();
        short8 af[4][2], bfr[4][2];
        #pragma unroll
        for (int ti = 0; ti < 4; ti++)
            #pragma unroll
            for (int ks = 0; ks < 2; ks++) {
                af[ti][ks]  = *(const short8*)(Ab + aoff[ti][ks]);
                bfr[ti][ks] = *(const short8*)(Bb + boff[ti][ks]);
            }
        #pragma unroll
        for (int ks = 0; ks < 2; ks++)
            #pragma unroll
            for (int ti = 0; ti < 4; ti++)
                #pragma unroll
                for (int tj = 0; tj < 4; tj++)
                    acc[ti][tj] = __builtin_amdgcn_mfma_f32_16x16x32_bf16(
                        af[ti][ks], bfr[tj][ks], acc[ti][tj], 0, 0, 0);
        __syncthreads();
    }

    #pragma unroll
    for (int ti = 0; ti < 4; ti++)
        #pragma unroll
        for (int tj = 0; tj < 4; tj++) {
            const int col = colBase + wn * 64 + tj * 16 + (lane & 15);
            #pragma unroll
            for (int reg = 0; reg < 4; reg++) {
                const int row = rowBase + wm * 64 + ti * 16 + (lane >> 4) * 4 + reg;
                Ybf[(size_t)row * 512 + col] = f2bf(acc[ti][tj][reg]);
            }
        }
}

// ---------------- kernel 3: bf16 MFMA GEMM 128x128 (round-9-proven) + XCD-chunked L2 swizzle ----------------
// grid 16384 x 256 (1-D). Decode: xcd = wg&7, idx = wg>>3; mtile = xcd*32 + (idx&31),
// ytile = idx>>5. 16384 % 8 == 0 -> bijective (ERRATA #11 safe). Neutral-to-slightly-positive
// vs round-9 linear decode (348 vs 356 us); kept for free locality.
__global__ __launch_bounds__(256) void k_gemm(const ushort_t* __restrict__ Y,
                                              const ushort_t* __restrict__ C,
                                              u32* __restrict__ part2) {
    __shared__ ushort_t Ab[128 * 64];
    __shared__ ushort_t Bb[128 * 64];
    __shared__ u32 tmp[128][2][2][2];   // [row][wn][grp][2]
    const int tid = threadIdx.x;
    const int lane = tid & 63;
    const int wid = tid >> 6;
    const int wm = wid & 1, wn = wid >> 1;

    const u32 wg = blockIdx.x;
    const u32 xcd = wg & 7u;
    const u32 idx = wg >> 3;
    const int mtile = (int)(xcd * 32u + (idx & 31u));
    const int ytile = (int)(idx >> 5);
    const int rowBase = mtile * 128;
    const int colBase = ytile * 128;

    const ushort_t* asrc[4];
    const ushort_t* bsrc[4];
    int ldsoff[4];
    #pragma unroll
    for (int i = 0; i < 4; i++) {
        const int L = i * 256 + tid;
        const int r = L >> 3;
        const int s = (L & 7) ^ (r & 7);
        asrc[i] = Y + (size_t)(rowBase + r) * 512 + s * 8;
        bsrc[i] = C + (size_t)(colBase + r) * 512 + s * 8;
        ldsoff[i] = (i * 256 + (tid & ~63)) * 16;
    }

    f32x4 acc[4][4];
    #pragma unroll
    for (int i = 0; i < 4; i++)
        #pragma unroll
        for (int j = 0; j < 4; j++) {
            f32x4 z = {16.f, 16.f, 16.f, 16.f};
            acc[i][j] = z;
        }

    int aoff[4][2], boff[4][2];
    #pragma unroll
    for (int ti = 0; ti < 4; ti++)
        #pragma unroll
        for (int ks = 0; ks < 2; ks++) {
            const int sa = ks * 4 + (lane >> 4);
            const int ra = wm * 64 + ti * 16 + (lane & 15);
            aoff[ti][ks] = (ra * 8 + (sa ^ (ra & 7))) * 8;
            const int rb = wn * 64 + ti * 16 + (lane & 15);
            boff[ti][ks] = (rb * 8 + (sa ^ (rb & 7))) * 8;
        }

    u32 ecol[4];
    #pragma unroll
    for (int tj = 0; tj < 4; tj++) ecol[tj] = 127u - (u32)(wn * 64 + tj * 16 + (lane & 15));

    for (int kt = 0; kt < 512; kt += 64) {
        #pragma unroll
        for (int i = 0; i < 4; i++) {
            __builtin_amdgcn_global_load_lds(
                (const __attribute__((address_space(1))) uint32_t*)(asrc[i] + kt),
                (__attribute__((address_space(3))) uint32_t*)((char*)Ab + ldsoff[i]), 16, 0, 0);
            __builtin_amdgcn_global_load_lds(
                (const __attribute__((address_space(1))) uint32_t*)(bsrc[i] + kt),
                (__attribute__((address_space(3))) uint32_t*)((char*)Bb + ldsoff[i]), 16, 0, 0);
        }
        __syncthreads();
        short8 af[4][2], bfr[4][2];
        #pragma unroll
        for (int ti = 0; ti < 4; ti++)
            #pragma unroll
            for (int ks = 0; ks < 2; ks++) {
                af[ti][ks]  = *(const short8*)(Ab + aoff[ti][ks]);
                bfr[ti][ks] = *(const short8*)(Bb + boff[ti][ks]);
            }
        #pragma unroll
        for (int ks = 0; ks < 2; ks++)
            #pragma unroll
            for (int ti = 0; ti < 4; ti++)
                #pragma unroll
                for (int tj = 0; tj < 4; tj++)
                    acc[ti][tj] = __builtin_amdgcn_mfma_f32_16x16x32_bf16(
                        af[ti][ks], bfr[tj][ks], acc[ti][tj], 0, 0, 0);
        __syncthreads();
    }

    // epilogue: embed col, per-thread top-2 of 4 cols, 3-step butterfly (8-lane groups)
    #pragma unroll
    for (int ti = 0; ti < 4; ti++)
        #pragma unroll
        for (int reg = 0; reg < 4; reg++) {
            float v0 = __uint_as_float((__float_as_uint(acc[ti][0][reg]) & 0xFFFFFF80u) | ecol[0]);
            float v1 = __uint_as_float((__float_as_uint(acc[ti][1][reg]) & 0xFFFFFF80u) | ecol[1]);
            float v2 = __uint_as_float((__float_as_uint(acc[ti][2][reg]) & 0xFFFFFF80u) | ecol[2]);
            float v3 = __uint_as_float((__float_as_uint(acc[ti][3][reg]) & 0xFFFFFF80u) | ecol[3]);
            float m1 = fmaxf(v0, v1);
            float m2 = fminf(v0, v1);
            float med = __builtin_amdgcn_fmed3f(m1, v2, v3);
            m1 = fmaxf(m1, fmaxf(v2, v3));
            m2 = fmaxf(m2, med);
            #pragma unroll
            for (int mk = 1; mk < 8; mk <<= 1) {
                float o1 = __shfl_xor(m1, mk, 64);
                float o2 = __shfl_xor(m2, mk, 64);
                merge_desc(m1, m2, o1, o2);
            }
            if ((lane & 7) == 0) {
                const int mrow = wm * 64 + ti * 16 + (lane >> 4) * 4 + reg;
                const int grp = (lane >> 3) & 1;
                tmp[mrow][wn][grp][0] = __float_as_uint(m1);
                tmp[mrow][wn][grp][1] = __float_as_uint(m2);
            }
        }
    __syncthreads();
    if (tid < 128) {
        float a1 = __uint_as_float(tmp[tid][0][0][0]), a2 = __uint_as_float(tmp[tid][0][0][1]);
        merge_desc(a1, a2, __uint_as_float(tmp[tid][0][1][0]), __uint_as_float(tmp[tid][0][1][1]));
        merge_desc(a1, a2, __uint_as_float(tmp[tid][1][0][0]), __uint_as_float(tmp[tid][1][0][1]));
        merge_desc(a1, a2, __uint_as_float(tmp[tid][1][1][0]), __uint_as_float(tmp[tid][1][1][1]));
        u32* dst = part2 + ((size_t)(rowBase + tid) * 64 + ytile) * 2;
        dst[0] = __float_as_uint(a1);
        dst[1] = __float_as_uint(a2);
    }
}

// ---------------- kernel 4: float-domain winner + margin flag (round-6-proven threshold) ----------------
// grid 8192 x 256 (wave per row).
__global__ __launch_bounds__(256) void k_pick(const u32* __restrict__ part2,
                                              const int* __restrict__ mask,
                                              int* __restrict__ out,
                                              u32* __restrict__ wl,
                                              u32* __restrict__ count) {
    const int row = blockIdx.x * 4 + (threadIdx.x >> 6);
    const int lane = threadIdx.x & 63;
    const u32* base = part2 + (size_t)row * 128;
    const u32 b0 = base[lane];
    const u32 b1 = base[64 + lane];
    // all keys are positive floats -> u32 order == float order
    float a1 = __uint_as_float(b0 > b1 ? b0 : b1);
    float a2 = __uint_as_float(b0 > b1 ? b1 : b0);
    #pragma unroll
    for (int mk = 1; mk < 64; mk <<= 1) {
        float o1 = __shfl_xor(a1, mk, 64);
        float o2 = __shfl_xor(a2, mk, 64);
        merge_desc(a1, a2, o1, o2);
    }
    // decode winner's global col: min col among keys bit-equal to the max
    const u32 w1 = __float_as_uint(a1);
    u32 c0 = (b0 == w1) ? ((u32)(lane >> 1) * 128u + (127u - (b0 & 0x7Fu))) : 0xFFFFu;
    u32 c1 = (b1 == w1) ? ((u32)((64 + lane) >> 1) * 128u + (127u - (b1 & 0x7Fu))) : 0xFFFFu;
    u32 cmin = c0 < c1 ? c0 : c1;
    #pragma unroll
    for (int mk = 1; mk < 64; mk <<= 1) {
        u32 oc = __shfl_xor(cmin, mk, 64);
        cmin = cmin < oc ? cmin : oc;
    }
    if (lane == 0) {
        out[row] = mask[row] ? (int)cmin : 0;
        // margin noise sigma ~= 2.3e-3 (bf16 operands, ||y||~22.6); round-6-proven
        // threshold = 0.006*|score| + 0.002 ~= 10 sigma at typical score 3.7.
        const float s1 = a1 - 16.0f;
        if (a1 - a2 < 0.006f * fabsf(s1) + 0.002f) {
            u32 pos = atomicAdd(count, 1u);
            wl[pos] = (u32)row;
        }
    }
}

// ---------------- kernel 5: exact fp64 fix, 4 rows/block (parallelism fix) ----------------
// grid 1024 x 256, grid-stride over worklist; 4 rows/block (one wave per row for staging
// and candidate extraction; fp64 projection cooperative across all 256 threads).
// Math identical to the proven 16-row version; only the block decomposition changed.
__global__ __launch_bounds__(256) void k_fix4(const float* __restrict__ x,
                                              const float* __restrict__ P,
                                              const float* __restrict__ cb,
                                              const u32* __restrict__ part2,
                                              const u32* __restrict__ wl,
                                              const u32* __restrict__ count,
                                              const int* __restrict__ mask,
                                              int* __restrict__ out) {
    __shared__ float xs[4][512];
    __shared__ u32 cands_s[4][8];
    __shared__ double nrmw[4][4];
    __shared__ double invn[4];
    __shared__ double wredD[4][8];
    __shared__ double wredC[4][8];
    __shared__ int bestIdx[4];
    const int tid = threadIdx.x;
    const int lane = tid & 63;
    const int wv = tid >> 6;
    const u32 n = *count;

    for (u32 basei = (u32)blockIdx.x * 4u; basei < n; basei += (u32)gridDim.x * 4u) {
        const int nr = (int)((n - basei < 4u) ? (n - basei) : 4u);
        __syncthreads();

        // stage x rows: wave wv stages row wv (clamped)
        {
            const int rc = wv < nr ? wv : nr - 1;
            const u32 ridx = wl[basei + rc];
            const float4* src = (const float4*)(x + (size_t)ridx * 512);
            float4* dst = (float4*)&xs[wv][0];
            dst[lane] = src[lane];
            dst[lane + 64] = src[lane + 64];
        }
        // extract top-8 candidates: wave wv handles row wv
        {
            const int rc = wv < nr ? wv : nr - 1;
            const u32 rowi = wl[basei + rc];
            const u32* base = part2 + (size_t)rowi * 128;
            const u32 b0 = base[lane];
            const u32 b1 = base[64 + lane];
            const u32 sc0 = b0 & 0xFFFFFF80u;
            const u32 sc1 = b1 & 0xFFFFFF80u;
            const u32 col0 = (u32)(lane >> 1) * 128u + (127u - (b0 & 0x7Fu));
            const u32 col1 = (u32)((64 + lane) >> 1) * 128u + (127u - (b1 & 0x7Fu));
            const u64 k0 = ((u64)(~sc0) << 13) | col0;
            const u64 k1 = ((u64)(~sc1) << 13) | col1;
            u64 t0 = k0 < k1 ? k0 : k1;
            u64 t1 = k0 < k1 ? k1 : k0;
            u64 t2 = ~0ull, t3 = ~0ull;
            butterfly4(t0, t1, t2, t3);
            const u64 g0 = t0, g1 = t1, g2 = t2, g3 = t3;
            u64 e0 = (k0 == g0 || k0 == g1 || k0 == g2 || k0 == g3) ? ~0ull : k0;
            u64 e1 = (k1 == g0 || k1 == g1 || k1 == g2 || k1 == g3) ? ~0ull : k1;
            u64 u0 = e0 < e1 ? e0 : e1;
            u64 u1 = e0 < e1 ? e1 : e0;
            u64 u2 = ~0ull, u3 = ~0ull;
            butterfly4(u0, u1, u2, u3);
            if (lane == 0) {
                cands_s[wv][0] = (u32)(g0 & 0x1FFFu); cands_s[wv][1] = (u32)(g1 & 0x1FFFu);
                cands_s[wv][2] = (u32)(g2 & 0x1FFFu); cands_s[wv][3] = (u32)(g3 & 0x1FFFu);
                cands_s[wv][4] = (u32)(u0 & 0x1FFFu); cands_s[wv][5] = (u32)(u1 & 0x1FFFu);
                cands_s[wv][6] = (u32)(u2 & 0x1FFFu); cands_s[wv][7] = (u32)(u3 & 0x1FFFu);
            }
        }
        __syncthreads();

        // fp64 projection: thread owns columns d0, d0+1 for all 4 rows
        const int d0 = tid * 2;
        double acc[4][2];
        #pragma unroll
        for (int r = 0; r < 4; r++) { acc[r][0] = 0.0; acc[r][1] = 0.0; }
        const float* pp = P + d0;
        for (int k = 0; k < 512; k += 2) {
            float2 pa = *(const float2*)(pp + (size_t)k * 512);
            float2 pb = *(const float2*)(pp + (size_t)(k + 1) * 512);
            const double pa0 = (double)pa.x, pa1 = (double)pa.y;
            const double pb0 = (double)pb.x, pb1 = (double)pb.y;
            #pragma unroll
            for (int r = 0; r < 4; r++) {
                float2 xv = *(const float2*)&xs[r][k];
                const double x0 = (double)xv.x, x1 = (double)xv.y;
                acc[r][0] = fma(x0, pa0, acc[r][0]);
                acc[r][1] = fma(x0, pa1, acc[r][1]);
                acc[r][0] = fma(x1, pb0, acc[r][0]);
                acc[r][1] = fma(x1, pb1, acc[r][1]);
            }
        }

        // fp64 row norms
        #pragma unroll
        for (int r = 0; r < 4; r++) {
            double s = fma(acc[r][0], acc[r][0], acc[r][1] * acc[r][1]);
            #pragma unroll
            for (int mk = 1; mk < 64; mk <<= 1) s += __shfl_xor(s, mk, 64);
            if (lane == 0) nrmw[wv][r] = s;
        }
        __syncthreads();
        if (tid < 4) {
            double t = nrmw[0][tid] + nrmw[1][tid] + nrmw[2][tid] + nrmw[3][tid];
            invn[tid] = 1.0 / fmax(sqrt(t), 1e-12);
        }
        __syncthreads();

        // rescore 8 candidates per row in fp64 from raw codebooks
        for (int r = 0; r < nr; r++) {
            const double xinv = invn[r];
            const double xn0 = acc[r][0] * xinv;
            const double xn1 = acc[r][1] * xinv;
            int vidx[8];
            double pd[8], pc[8];
            #pragma unroll
            for (int c = 0; c < 8; c++) {
                vidx[c] = (int)cands_s[r][c];
                float2 cv = *(const float2*)(cb + (size_t)vidx[c] * 512 + d0);
                const double c0 = (double)cv.x, c1 = (double)cv.y;
                pd[c] = fma(c0, xn0, c1 * xn1);
                pc[c] = fma(c0, c0, c1 * c1);
            }
            #pragma unroll
            for (int mk = 1; mk < 64; mk <<= 1) {
                #pragma unroll
                for (int c = 0; c < 8; c++) {
                    pd[c] += __shfl_xor(pd[c], mk, 64);
                    pc[c] += __shfl_xor(pc[c], mk, 64);
                }
            }
            if (lane == 0) {
                #pragma unroll
                for (int c = 0; c < 8; c++) { wredD[wv][c] = pd[c]; wredC[wv][c] = pc[c]; }
            }
            __syncthreads();
            if (tid == 0) {
                double bs = -1.0e300;
                int bi = 0x7fffffff;
                #pragma unroll
                for (int c = 0; c < 8; c++) {
                    const double D = wredD[0][c] + wredD[1][c] + wredD[2][c] + wredD[3][c];
                    const double Cw = wredC[0][c] + wredC[1][c] + wredC[2][c] + wredC[3][c];
                    const double s = D / fmax(sqrt(Cw), 1e-12);
                    const int v = vidx[c];
                    if (s > bs || (s == bs && v < bi)) { bs = s; bi = v; }
                }
                bestIdx[r] = bi;
            }
            __syncthreads();
        }

        if (tid < nr) {
            const u32 row = wl[basei + tid];
            out[row] = mask[row] ? bestIdx[tid] : 0;
        }
    }
}

// ---------------- launcher ----------------
extern "C" void kernel_launch(void* const* d_in, const int* in_sizes, int n_in,
                              void* d_out, int out_size, void* d_ws, size_t ws_size,
                              hipStream_t stream) {
    const float* x = (const float*)d_in[0];               // [32768,512] fp32
    const int* mask = (const int*)d_in[1];                // [32768] bool->int32
    const float* projection = (const float*)d_in[2];      // [512,512] fp32
    const float* codebooks = (const float*)d_in[3];       // [8192,512] fp32
    int* out = (int*)d_out;                               // [32768] int32

    // workspace (~75 MB): xbf dead after k_proj -> part2 aliases it.
    char* ws = (char*)d_ws;
    ushort_t* xbf = (ushort_t*)ws;                         // 32 MB [0,32)
    u32* part2    = (u32*)ws;                              // 16 MB (aliases xbf)
    ushort_t* ybf = (ushort_t*)(ws + (32u << 20));         // 32 MB [32,64)
    ushort_t* cbf = (ushort_t*)(ws + (64u << 20));         // 8 MB  [64,72)
    ushort_t* pbT = (ushort_t*)(ws + (72u << 20));         // 512 KB
    u32* wl       = (u32*)(ws + (73u << 20));              // 128 KB
    u32* count    = (u32*)(ws + (74u << 20));              // 4 B

    k_prep<<<4160, 256, 0, stream>>>(x, projection, codebooks, xbf, pbT, cbf, count);
    k_proj<<<dim3(256, 4), 256, 0, stream>>>(xbf, pbT, ybf);
    k_gemm<<<16384, 256, 0, stream>>>(ybf, cbf, part2);
    k_pick<<<8192, 256, 0, stream>>>(part2, mask, out, wl, count);
    k_fix4<<<1024, 256, 0, stream>>>(x, projection, codebooks, part2, wl, count,
                                     mask, out);
}